// Round 1
// baseline (3269.085 us; speedup 1.0000x reference)
//
#include <hip/hip_runtime.h>
#include <cstddef>
#include <cstdint>
#include <math.h>

// Problem constants (B=1)
#define kS    2048
#define kDim  2048
#define kH    16
#define kG    2
#define kDH   128
#define kRep  8     // H / G
#define kL    32    // compression window
#define kDstr 16    // compression stride
#define kLP   32    // selection block
#define kNSel 16
#define kW    256   // sliding window
#define kJ    127   // (S - L)/D + 1
#define kNB   64    // S / LP
#define kScale 0.08838834764831845f

// ---------------------------------------------------------------------------
// Tiled f32 GEMM: C[M,N] = A[M,K] @ B[K,N], row-major, M%128==0, N%128==0, K%16==0
// ---------------------------------------------------------------------------
__global__ __launch_bounds__(256) void gemm_f32_kernel(
    const float* __restrict__ A, const float* __restrict__ B,
    float* __restrict__ C, int M, int N, int K) {
  __shared__ float As[128][17];
  __shared__ float Bs[16][128];
  const int t = threadIdx.x;
  const int tx = t & 15;
  const int ty = t >> 4;
  const size_t row0 = (size_t)blockIdx.y * 128;
  const size_t col0 = (size_t)blockIdx.x * 128;
  float acc[8][8];
#pragma unroll
  for (int i = 0; i < 8; ++i)
#pragma unroll
    for (int j = 0; j < 8; ++j) acc[i][j] = 0.f;

  for (int k0 = 0; k0 < K; k0 += 16) {
#pragma unroll
    for (int i = 0; i < 2; ++i) {
      int lin = t + i * 256;          // 0..511 -> 128 rows x 4 float4
      int r = lin >> 2;
      int c = (lin & 3) << 2;
      const float4 av = *reinterpret_cast<const float4*>(
          &A[(row0 + r) * (size_t)K + k0 + c]);
      As[r][c + 0] = av.x; As[r][c + 1] = av.y;
      As[r][c + 2] = av.z; As[r][c + 3] = av.w;
    }
#pragma unroll
    for (int i = 0; i < 2; ++i) {
      int lin = t + i * 256;          // 16 rows x 32 float4
      int r = lin >> 5;
      int c = (lin & 31) << 2;
      *reinterpret_cast<float4*>(&Bs[r][c]) =
          *reinterpret_cast<const float4*>(&B[(size_t)(k0 + r) * N + col0 + c]);
    }
    __syncthreads();
#pragma unroll
    for (int kk = 0; kk < 16; ++kk) {
      float a[8], b[8];
#pragma unroll
      for (int i = 0; i < 8; ++i) a[i] = As[ty * 8 + i][kk];
      float4 b0 = *reinterpret_cast<const float4*>(&Bs[kk][tx * 8]);
      float4 b1 = *reinterpret_cast<const float4*>(&Bs[kk][tx * 8 + 4]);
      b[0] = b0.x; b[1] = b0.y; b[2] = b0.z; b[3] = b0.w;
      b[4] = b1.x; b[5] = b1.y; b[6] = b1.z; b[7] = b1.w;
#pragma unroll
      for (int i = 0; i < 8; ++i)
#pragma unroll
        for (int j = 0; j < 8; ++j)
          acc[i][j] = fmaf(a[i], b[j], acc[i][j]);
    }
    __syncthreads();
  }
#pragma unroll
  for (int i = 0; i < 8; ++i) {
    size_t roff = (row0 + ty * 8 + i) * (size_t)N + col0 + tx * 8;
    float4 v0 = make_float4(acc[i][0], acc[i][1], acc[i][2], acc[i][3]);
    float4 v1 = make_float4(acc[i][4], acc[i][5], acc[i][6], acc[i][7]);
    *reinterpret_cast<float4*>(&C[roff]) = v0;
    *reinterpret_cast<float4*>(&C[roff + 4]) = v1;
  }
}

// ---------------------------------------------------------------------------
// RoPE (interleaved pairs), in place. t: (S, nheads, DH)
// ---------------------------------------------------------------------------
__global__ void rope_kernel(float* __restrict__ tb, const float* __restrict__ fc,
                            const float* __restrict__ fsn, int nheads, int total) {
  int idx = blockIdx.x * blockDim.x + threadIdx.x;
  if (idx >= total) return;
  int i = idx & 63;                  // pair index 0..63
  int h = (idx >> 6) % nheads;
  int s = idx / (64 * nheads);
  float c = fc[s * 64 + i];
  float sn = fsn[s * 64 + i];
  float* p = tb + ((size_t)s * nheads + h) * kDH + 2 * i;
  float x0 = p[0], x1 = p[1];
  p[0] = x0 * c - x1 * sn;
  p[1] = x0 * sn + x1 * c;
}

// ---------------------------------------------------------------------------
// Compression mean-pool: kc/vc (J, G, DH) = mean over 32 tokens, stride 16
// ---------------------------------------------------------------------------
__global__ void pool_kernel(const float* __restrict__ k, const float* __restrict__ v,
                            float* __restrict__ kc, float* __restrict__ vc) {
  int idx = blockIdx.x * blockDim.x + threadIdx.x;
  if (idx >= kJ * kG * kDH) return;
  int d = idx & 127;
  int g = (idx >> 7) & 1;
  int j = idx >> 8;
  float sk = 0.f, sv = 0.f;
  for (int l = 0; l < kL; ++l) {
    size_t off = ((size_t)(j * kDstr + l) * kG + g) * kDH + d;
    sk += k[off];
    sv += v[off];
  }
  kc[idx] = sk * (1.f / 32.f);
  vc[idx] = sv * (1.f / 32.f);
}

// ---------------------------------------------------------------------------
// Per (s,g): compressed attention (o_cmp), importance, top-k block mask, gates
// ---------------------------------------------------------------------------
__global__ __launch_bounds__(256) void cmp_attn_kernel(
    const float* __restrict__ q, const float* __restrict__ kc,
    const float* __restrict__ vc, const float* __restrict__ wg,
    float* __restrict__ oc, float* __restrict__ gates,
    unsigned long long* __restrict__ selmask) {
  const int sg = blockIdx.x;
  const int s = sg >> 1;
  const int g = sg & 1;
  const int t = threadIdx.x;
  __shared__ float qs[kRep * kDH];
  __shared__ float p[kRep][kJ + 1];
  __shared__ float imp[kNB];
  {
    const float* src = q + ((size_t)s * kH + g * kRep) * kDH;
    *reinterpret_cast<float4*>(&qs[t * 4]) =
        *reinterpret_cast<const float4*>(&src[t * 4]);
  }
  __syncthreads();
  const int jmax = (s >= kL - 1) ? ((s - (kL - 1)) >> 4) : -1;  // inclusive
  // scores
  for (int task = t; task < kRep * kJ; task += 256) {
    int r = task & 7;
    int j = task >> 3;
    float sc = -INFINITY;
    if (j <= jmax) {
      const float* kr = kc + ((size_t)j * kG + g) * kDH;
      const float* qr = qs + r * kDH;
      float acc = 0.f;
      for (int d = 0; d < kDH; d += 4) {
        float4 qv = *reinterpret_cast<const float4*>(&qr[d]);
        float4 kv = *reinterpret_cast<const float4*>(&kr[d]);
        acc = fmaf(qv.x, kv.x, acc);
        acc = fmaf(qv.y, kv.y, acc);
        acc = fmaf(qv.z, kv.z, acc);
        acc = fmaf(qv.w, kv.w, acc);
      }
      sc = acc * kScale;
    }
    p[r][j] = sc;
  }
  __syncthreads();
  // softmax per head-row (invalid -> 0; no-valid -> all 0, matching reference)
  if (t < kRep) {
    int r = t;
    if (jmax < 0) {
      for (int j = 0; j < kJ; ++j) p[r][j] = 0.f;
    } else {
      float m = -INFINITY;
      for (int j = 0; j <= jmax; ++j) m = fmaxf(m, p[r][j]);
      float sum = 0.f;
      for (int j = 0; j <= jmax; ++j) {
        float e = __expf(p[r][j] - m);
        p[r][j] = e;
        sum += e;
      }
      float inv = 1.f / sum;
      for (int j = 0; j <= jmax; ++j) p[r][j] *= inv;
      for (int j = jmax + 1; j < kJ; ++j) p[r][j] = 0.f;
    }
  }
  __syncthreads();
  // o_cmp = p @ v_cmp
  for (int task = t; task < kRep * kDH; task += 256) {
    int r = task >> 7;
    int d = task & 127;
    float acc = 0.f;
    for (int j = 0; j <= jmax; ++j)
      acc = fmaf(p[r][j], vc[((size_t)j * kG + g) * kDH + d], acc);
    oc[((size_t)s * kH + g * kRep + r) * kDH + d] = acc;
  }
  // importance per selection block m: sum_r (p[2m-1] + p[2m] + p[2m+1])
  const int mcur = s >> 5;
  if (t < kNB) {
    int m = t;
    float im;
    if (m > mcur) {
      im = -INFINITY;
    } else {
      im = 0.f;
      for (int r = 0; r < kRep; ++r) {
        float sump = p[r][2 * m];
        if (2 * m - 1 >= 0) sump += p[r][2 * m - 1];
        if (2 * m + 1 < kJ) sump += p[r][2 * m + 1];
        im += sump;
      }
      if (m == 0) im += 1e9f;
      if (m == mcur) im += 1e9f;
    }
    imp[m] = im;
  }
  __syncthreads();
  // top-k (strict >, first-index wins on ties == jax.lax.top_k stable order)
  if (t == 0) {
    unsigned long long mask = 0ull;
    for (int it = 0; it < kNSel; ++it) {
      float best = -INFINITY;
      int bi = -1;
      for (int m = 0; m < kNB; ++m) {
        if ((mask >> m) & 1ull) continue;
        float v2 = imp[m];
        if (bi < 0 || v2 > best) { best = v2; bi = m; }
      }
      mask |= (1ull << bi);
    }
    selmask[sg] = mask;
  }
  // gates = sigmoid(q @ w_g)
  if (t < kRep * 3) {
    int r = t / 3;
    int e = t - r * 3;
    const float* qr = qs + r * kDH;
    float acc = 0.f;
    for (int d = 0; d < kDH; ++d) acc = fmaf(qr[d], wg[d * 3 + e], acc);
    gates[((size_t)sg * kRep + r) * 3 + e] = 1.f / (1.f + __expf(-acc));
  }
}

// ---------------------------------------------------------------------------
// Per (s,g): selected-block attention + sliding-window attention + combine
// ---------------------------------------------------------------------------
__global__ __launch_bounds__(256) void sel_sw_kernel(
    const float* __restrict__ q, const float* __restrict__ k,
    const float* __restrict__ v, const float* __restrict__ oc,
    const float* __restrict__ gates,
    const unsigned long long* __restrict__ selmask,
    float* __restrict__ outp) {
  const int sg = blockIdx.x;
  const int s = sg >> 1;
  const int g = sg & 1;
  const int t = threadIdx.x;
  __shared__ float qs[kRep * kDH];
  __shared__ float ps[kRep][kNSel * kLP];   // 8 x 512
  __shared__ int blk[kNSel];
  __shared__ int nblk_sh;
  {
    const float* src = q + ((size_t)s * kH + g * kRep) * kDH;
    *reinterpret_cast<float4*>(&qs[t * 4]) =
        *reinterpret_cast<const float4*>(&src[t * 4]);
  }
  if (t == 0) {
    unsigned long long mask = selmask[sg];
    int mcur = s >> 5;
    int n = 0;
    for (int m = 0; m <= mcur; ++m)
      if ((mask >> m) & 1ull) blk[n++] = m;
    nblk_sh = n;
  }
  __syncthreads();
  const int nblk = nblk_sh;
  const int ns = nblk * kLP;
  // ---- selected scores ----
  for (int task = t; task < kRep * ns; task += 256) {
    int r = task & 7;
    int tl = task >> 3;
    int tok = blk[tl >> 5] * kLP + (tl & 31);
    float sc = -INFINITY;
    if (tok <= s) {
      const float* kr = k + ((size_t)tok * kG + g) * kDH;
      const float* qr = qs + r * kDH;
      float acc = 0.f;
      for (int d = 0; d < kDH; d += 4) {
        float4 qv = *reinterpret_cast<const float4*>(&qr[d]);
        float4 kv = *reinterpret_cast<const float4*>(&kr[d]);
        acc = fmaf(qv.x, kv.x, acc);
        acc = fmaf(qv.y, kv.y, acc);
        acc = fmaf(qv.z, kv.z, acc);
        acc = fmaf(qv.w, kv.w, acc);
      }
      sc = acc * kScale;
    }
    ps[r][tl] = sc;
  }
  __syncthreads();
  // softmax per head-row (32-lane group per r)
  {
    int r = t >> 5;
    int lane = t & 31;
    float m = -INFINITY;
    for (int tl = lane; tl < ns; tl += 32) m = fmaxf(m, ps[r][tl]);
#pragma unroll
    for (int o = 16; o > 0; o >>= 1) m = fmaxf(m, __shfl_xor(m, o, 32));
    float sum = 0.f;
    for (int tl = lane; tl < ns; tl += 32) {
      float e = __expf(ps[r][tl] - m);
      ps[r][tl] = e;
      sum += e;
    }
#pragma unroll
    for (int o = 16; o > 0; o >>= 1) sum += __shfl_xor(sum, o, 32);
    float inv = 1.f / sum;
    for (int tl = lane; tl < ns; tl += 32) ps[r][tl] *= inv;
  }
  __syncthreads();
  float osel[4], osw[4];
#pragma unroll
  for (int u = 0; u < 4; ++u) {
    int ti = t + u * 256;
    int r = ti >> 7;
    int d = ti & 127;
    float acc = 0.f;
    for (int tl = 0; tl < ns; ++tl) {
      int tok = blk[tl >> 5] * kLP + (tl & 31);
      acc = fmaf(ps[r][tl], v[((size_t)tok * kG + g) * kDH + d], acc);
    }
    osel[u] = acc;
  }
  __syncthreads();
  // ---- sliding window ----
  int t0 = s - (kW - 1);
  if (t0 < 0) t0 = 0;
  const int nt = s - t0 + 1;
  for (int task = t; task < kRep * nt; task += 256) {
    int r = task & 7;
    int tl = task >> 3;
    int tok = t0 + tl;
    const float* kr = k + ((size_t)tok * kG + g) * kDH;
    const float* qr = qs + r * kDH;
    float acc = 0.f;
    for (int d = 0; d < kDH; d += 4) {
      float4 qv = *reinterpret_cast<const float4*>(&qr[d]);
      float4 kv = *reinterpret_cast<const float4*>(&kr[d]);
      acc = fmaf(qv.x, kv.x, acc);
      acc = fmaf(qv.y, kv.y, acc);
      acc = fmaf(qv.z, kv.z, acc);
      acc = fmaf(qv.w, kv.w, acc);
    }
    ps[r][tl] = acc * kScale;
  }
  __syncthreads();
  {
    int r = t >> 5;
    int lane = t & 31;
    float m = -INFINITY;
    for (int tl = lane; tl < nt; tl += 32) m = fmaxf(m, ps[r][tl]);
#pragma unroll
    for (int o = 16; o > 0; o >>= 1) m = fmaxf(m, __shfl_xor(m, o, 32));
    float sum = 0.f;
    for (int tl = lane; tl < nt; tl += 32) {
      float e = __expf(ps[r][tl] - m);
      ps[r][tl] = e;
      sum += e;
    }
#pragma unroll
    for (int o = 16; o > 0; o >>= 1) sum += __shfl_xor(sum, o, 32);
    float inv = 1.f / sum;
    for (int tl = lane; tl < nt; tl += 32) ps[r][tl] *= inv;
  }
  __syncthreads();
#pragma unroll
  for (int u = 0; u < 4; ++u) {
    int ti = t + u * 256;
    int r = ti >> 7;
    int d = ti & 127;
    float acc = 0.f;
    for (int tl = 0; tl < nt; ++tl)
      acc = fmaf(ps[r][tl], v[((size_t)(t0 + tl) * kG + g) * kDH + d], acc);
    osw[u] = acc;
  }
  // ---- combine with gates + o_cmp ----
#pragma unroll
  for (int u = 0; u < 4; ++u) {
    int ti = t + u * 256;
    int r = ti >> 7;
    int d = ti & 127;
    const float* gg = gates + ((size_t)sg * kRep + r) * 3;
    size_t off = ((size_t)s * kH + g * kRep + r) * kDH + d;
    outp[off] = gg[0] * oc[off] + gg[1] * osel[u] + gg[2] * osw[u];
  }
}

// ---------------------------------------------------------------------------
extern "C" void kernel_launch(void* const* d_in, const int* in_sizes, int n_in,
                              void* d_out, int out_size, void* d_ws, size_t ws_size,
                              hipStream_t stream) {
  (void)in_sizes; (void)n_in; (void)out_size; (void)ws_size;
  const float* x  = (const float*)d_in[0];
  const float* fc = (const float*)d_in[1];
  const float* fs = (const float*)d_in[2];
  const float* wq = (const float*)d_in[3];
  const float* wk = (const float*)d_in[4];
  const float* wv = (const float*)d_in[5];
  const float* wv_o = (const float*)d_in[6];
  const float* wg = (const float*)d_in[7];
  float* out = (float*)d_out;

  float* ws = (float*)d_ws;
  float* q    = ws;                         // S*H*DH      = 4194304
  float* kbuf = q + 4194304;                // S*G*DH      = 524288
  float* vbuf = kbuf + 524288;              // 524288
  float* kc   = vbuf + 524288;              // J*G*DH      = 32512
  float* vc   = kc + 32512;                 // 32512
  float* oc   = vc + 32512;                 // 4194304
  float* gts  = oc + 4194304;               // S*G*REP*3   = 98304
  float* pre  = gts + 98304;                // 4194304
  unsigned long long* selmask = (unsigned long long*)(pre + 4194304);  // 4096

  dim3 blk256(256);
  // projections
  gemm_f32_kernel<<<dim3(16, 16), blk256, 0, stream>>>(x, wq, q, kS, kH * kDH, kDim);
  gemm_f32_kernel<<<dim3(2, 16), blk256, 0, stream>>>(x, wk, kbuf, kS, kG * kDH, kDim);
  gemm_f32_kernel<<<dim3(2, 16), blk256, 0, stream>>>(x, wv, vbuf, kS, kG * kDH, kDim);
  // rope on q and k
  rope_kernel<<<8192, blk256, 0, stream>>>(q, fc, fs, kH, kS * kH * 64);
  rope_kernel<<<1024, blk256, 0, stream>>>(kbuf, fc, fs, kG, kS * kG * 64);
  // compression pooling
  pool_kernel<<<128, blk256, 0, stream>>>(kbuf, vbuf, kc, vc);
  // compressed attention + importance + top-k + gates
  cmp_attn_kernel<<<kS * kG, blk256, 0, stream>>>(q, kc, vc, wg, oc, gts, selmask);
  // selected + sliding attention + gated combine
  sel_sw_kernel<<<kS * kG, blk256, 0, stream>>>(q, kbuf, vbuf, oc, gts, selmask, pre);
  // output projection
  gemm_f32_kernel<<<dim3(16, 16), blk256, 0, stream>>>(pre, wv_o, out, kS, kDim, kH * kDH);
}

// Round 2
// 2297.333 us; speedup vs baseline: 1.4230x; 1.4230x over previous
//
#include <hip/hip_runtime.h>
#include <cstddef>
#include <cstdint>
#include <math.h>

// Problem constants (B=1)
#define kS    2048
#define kDim  2048
#define kH    16
#define kG    2
#define kDH   128
#define kRep  8     // H / G
#define kL    32    // compression window
#define kDstr 16    // compression stride
#define kLP   32    // selection block
#define kNSel 16
#define kW    256   // sliding window
#define kJ    127   // (S - L)/D + 1
#define kNB   64    // S / LP
#define kScale 0.08838834764831845f

typedef __attribute__((ext_vector_type(4))) float f32x4;
typedef __attribute__((ext_vector_type(8))) __bf16 bf16x8;

__device__ __forceinline__ unsigned short f2bf(float f) {
  unsigned u = __float_as_uint(f);
  u += 0x7fff + ((u >> 16) & 1);   // RNE (finite values only)
  return (unsigned short)(u >> 16);
}

// ---------------------------------------------------------------------------
// f32 -> bf16 cast (vectorized, n4 = n/4)
// ---------------------------------------------------------------------------
__global__ void cast_bf16_kernel(const float* __restrict__ in,
                                 unsigned short* __restrict__ out, int n4) {
  int i = blockIdx.x * blockDim.x + threadIdx.x;
  if (i >= n4) return;
  float4 v = reinterpret_cast<const float4*>(in)[i];
  ushort4 o;
  o.x = f2bf(v.x); o.y = f2bf(v.y); o.z = f2bf(v.z); o.w = f2bf(v.w);
  reinterpret_cast<ushort4*>(out)[i] = o;
}

// ---------------------------------------------------------------------------
// transpose + cast: in[rows][cols] f32 -> out[cols][rows] bf16
// ---------------------------------------------------------------------------
__global__ __launch_bounds__(256) void transpose_cast_kernel(
    const float* __restrict__ in, unsigned short* __restrict__ out,
    int rows, int cols) {
  __shared__ float tile[32][33];
  const int bx = blockIdx.x * 32;   // col
  const int by = blockIdx.y * 32;   // row
  const int tx = threadIdx.x & 31;
  const int ty = threadIdx.x >> 5;
#pragma unroll
  for (int i = 0; i < 32; i += 8)
    tile[ty + i][tx] = in[(size_t)(by + ty + i) * cols + bx + tx];
  __syncthreads();
#pragma unroll
  for (int i = 0; i < 32; i += 8)
    out[(size_t)(bx + ty + i) * rows + by + tx] = f2bf(tile[tx][ty + i]);
}

// ---------------------------------------------------------------------------
// bf16 MFMA GEMM (m97 structure): C[M][N] f32 = A[M][K] x Bt[N][K]^T
// 128x128 tile, BK=32, 256 threads (4 waves, 2x2 wave grid of 64x64),
// global_load_lds width-16 staging, 16x16x32 bf16 MFMA, 4x4 frags/wave.
// M,N multiples of 128; K multiple of 32.
// ---------------------------------------------------------------------------
__global__ __launch_bounds__(256) void gemm_bf16_kernel(
    const unsigned short* __restrict__ A,   // [M][K] bf16 bits
    const unsigned short* __restrict__ Bt,  // [N][K] bf16 bits
    float* __restrict__ C, int M, int N, int K) {
  __shared__ unsigned short As[128 * 32];
  __shared__ unsigned short Bs[128 * 32];
  const int t = threadIdx.x;
  const int lane = t & 63;
  const int wid = t >> 6;
  const int wr = wid >> 1, wc = wid & 1;
  const int lhi = lane >> 4, llo = lane & 15;
  const size_t row0 = (size_t)blockIdx.y * 128;
  const size_t col0 = (size_t)blockIdx.x * 128;

  f32x4 acc[4][4];
#pragma unroll
  for (int m = 0; m < 4; ++m)
#pragma unroll
    for (int n = 0; n < 4; ++n) acc[m][n] = f32x4{0.f, 0.f, 0.f, 0.f};

  // staging geometry: 8KB tile = 4096 shorts; thread t covers elems e, e+2048
  const int e0 = t * 8;
  const int e1 = 2048 + t * 8;
  const int r0 = e0 >> 5, kk0 = e0 & 31;
  const int r1 = e1 >> 5, kk1 = e1 & 31;

  for (int k0 = 0; k0 < K; k0 += 32) {
    __builtin_amdgcn_global_load_lds(
        (const __attribute__((address_space(1))) unsigned int*)(A + (row0 + r0) * (size_t)K + k0 + kk0),
        (__attribute__((address_space(3))) unsigned int*)(As + e0), 16, 0, 0);
    __builtin_amdgcn_global_load_lds(
        (const __attribute__((address_space(1))) unsigned int*)(A + (row0 + r1) * (size_t)K + k0 + kk1),
        (__attribute__((address_space(3))) unsigned int*)(As + e1), 16, 0, 0);
    __builtin_amdgcn_global_load_lds(
        (const __attribute__((address_space(1))) unsigned int*)(Bt + (col0 + r0) * (size_t)K + k0 + kk0),
        (__attribute__((address_space(3))) unsigned int*)(Bs + e0), 16, 0, 0);
    __builtin_amdgcn_global_load_lds(
        (const __attribute__((address_space(1))) unsigned int*)(Bt + (col0 + r1) * (size_t)K + k0 + kk1),
        (__attribute__((address_space(3))) unsigned int*)(Bs + e1), 16, 0, 0);
    __syncthreads();   // drains vmcnt before any wave proceeds
    bf16x8 af[4], bfr[4];
#pragma unroll
    for (int m = 0; m < 4; ++m)
      af[m] = *reinterpret_cast<const bf16x8*>(&As[(wr * 64 + m * 16 + llo) * 32 + lhi * 8]);
#pragma unroll
    for (int n = 0; n < 4; ++n)
      bfr[n] = *reinterpret_cast<const bf16x8*>(&Bs[(wc * 64 + n * 16 + llo) * 32 + lhi * 8]);
#pragma unroll
    for (int m = 0; m < 4; ++m)
#pragma unroll
      for (int n = 0; n < 4; ++n)
        acc[m][n] = __builtin_amdgcn_mfma_f32_16x16x32_bf16(af[m], bfr[n], acc[m][n], 0, 0, 0);
    __syncthreads();
  }
  // C/D layout: col = lane&15, row = (lane>>4)*4 + j  [verified m89/m91]
#pragma unroll
  for (int m = 0; m < 4; ++m)
#pragma unroll
    for (int n = 0; n < 4; ++n)
#pragma unroll
      for (int j = 0; j < 4; ++j) {
        size_t r = row0 + wr * 64 + m * 16 + lhi * 4 + j;
        size_t c = col0 + wc * 64 + n * 16 + llo;
        C[r * (size_t)N + c] = acc[m][n][j];
      }
}

// ---------------------------------------------------------------------------
// RoPE (interleaved pairs), in place. t: (S, nheads, DH)
// ---------------------------------------------------------------------------
__global__ void rope_kernel(float* __restrict__ tb, const float* __restrict__ fc,
                            const float* __restrict__ fsn, int nheads, int total) {
  int idx = blockIdx.x * blockDim.x + threadIdx.x;
  if (idx >= total) return;
  int i = idx & 63;                  // pair index 0..63
  int h = (idx >> 6) % nheads;
  int s = idx / (64 * nheads);
  float c = fc[s * 64 + i];
  float sn = fsn[s * 64 + i];
  float* p = tb + ((size_t)s * nheads + h) * kDH + 2 * i;
  float x0 = p[0], x1 = p[1];
  p[0] = x0 * c - x1 * sn;
  p[1] = x0 * sn + x1 * c;
}

// ---------------------------------------------------------------------------
// Compression mean-pool: kc/vc (J, G, DH) = mean over 32 tokens, stride 16
// ---------------------------------------------------------------------------
__global__ void pool_kernel(const float* __restrict__ k, const float* __restrict__ v,
                            float* __restrict__ kc, float* __restrict__ vc) {
  int idx = blockIdx.x * blockDim.x + threadIdx.x;
  if (idx >= kJ * kG * kDH) return;
  int d = idx & 127;
  int g = (idx >> 7) & 1;
  int j = idx >> 8;
  float sk = 0.f, sv = 0.f;
  for (int l = 0; l < kL; ++l) {
    size_t off = ((size_t)(j * kDstr + l) * kG + g) * kDH + d;
    sk += k[off];
    sv += v[off];
  }
  kc[idx] = sk * (1.f / 32.f);
  vc[idx] = sv * (1.f / 32.f);
}

// ---------------------------------------------------------------------------
// Per (s,g): compressed attention (o_cmp), importance, top-k block mask, gates
// (kept fully f32 — owns the discrete block selection)
// ---------------------------------------------------------------------------
__global__ __launch_bounds__(256) void cmp_attn_kernel(
    const float* __restrict__ q, const float* __restrict__ kc,
    const float* __restrict__ vc, const float* __restrict__ wg,
    float* __restrict__ oc, float* __restrict__ gates,
    unsigned long long* __restrict__ selmask) {
  const int sg = blockIdx.x;
  const int s = sg >> 1;
  const int g = sg & 1;
  const int t = threadIdx.x;
  __shared__ float qs[kRep * kDH];
  __shared__ float p[kRep][kJ + 1];
  __shared__ float imp[kNB];
  {
    const float* src = q + ((size_t)s * kH + g * kRep) * kDH;
    *reinterpret_cast<float4*>(&qs[t * 4]) =
        *reinterpret_cast<const float4*>(&src[t * 4]);
  }
  __syncthreads();
  const int jmax = (s >= kL - 1) ? ((s - (kL - 1)) >> 4) : -1;  // inclusive
  for (int task = t; task < kRep * kJ; task += 256) {
    int r = task & 7;
    int j = task >> 3;
    float sc = -INFINITY;
    if (j <= jmax) {
      const float* kr = kc + ((size_t)j * kG + g) * kDH;
      const float* qr = qs + r * kDH;
      float acc = 0.f;
      for (int d = 0; d < kDH; d += 4) {
        float4 qv = *reinterpret_cast<const float4*>(&qr[d]);
        float4 kv = *reinterpret_cast<const float4*>(&kr[d]);
        acc = fmaf(qv.x, kv.x, acc);
        acc = fmaf(qv.y, kv.y, acc);
        acc = fmaf(qv.z, kv.z, acc);
        acc = fmaf(qv.w, kv.w, acc);
      }
      sc = acc * kScale;
    }
    p[r][j] = sc;
  }
  __syncthreads();
  if (t < kRep) {
    int r = t;
    if (jmax < 0) {
      for (int j = 0; j < kJ; ++j) p[r][j] = 0.f;
    } else {
      float m = -INFINITY;
      for (int j = 0; j <= jmax; ++j) m = fmaxf(m, p[r][j]);
      float sum = 0.f;
      for (int j = 0; j <= jmax; ++j) {
        float e = __expf(p[r][j] - m);
        p[r][j] = e;
        sum += e;
      }
      float inv = 1.f / sum;
      for (int j = 0; j <= jmax; ++j) p[r][j] *= inv;
      for (int j = jmax + 1; j < kJ; ++j) p[r][j] = 0.f;
    }
  }
  __syncthreads();
  for (int task = t; task < kRep * kDH; task += 256) {
    int r = task >> 7;
    int d = task & 127;
    float acc = 0.f;
    for (int j = 0; j <= jmax; ++j)
      acc = fmaf(p[r][j], vc[((size_t)j * kG + g) * kDH + d], acc);
    oc[((size_t)s * kH + g * kRep + r) * kDH + d] = acc;
  }
  const int mcur = s >> 5;
  if (t < kNB) {
    int m = t;
    float im;
    if (m > mcur) {
      im = -INFINITY;
    } else {
      im = 0.f;
      for (int r = 0; r < kRep; ++r) {
        float sump = p[r][2 * m];
        if (2 * m - 1 >= 0) sump += p[r][2 * m - 1];
        if (2 * m + 1 < kJ) sump += p[r][2 * m + 1];
        im += sump;
      }
      if (m == 0) im += 1e9f;
      if (m == mcur) im += 1e9f;
    }
    imp[m] = im;
  }
  __syncthreads();
  if (t == 0) {
    unsigned long long mask = 0ull;
    for (int it = 0; it < kNSel; ++it) {
      float best = -INFINITY;
      int bi = -1;
      for (int m = 0; m < kNB; ++m) {
        if ((mask >> m) & 1ull) continue;
        float v2 = imp[m];
        if (bi < 0 || v2 > best) { best = v2; bi = m; }
      }
      mask |= (1ull << bi);
    }
    selmask[sg] = mask;
  }
  if (t < kRep * 3) {
    int r = t / 3;
    int e = t - r * 3;
    const float* qr = qs + r * kDH;
    float acc = 0.f;
    for (int d = 0; d < kDH; ++d) acc = fmaf(qr[d], wg[d * 3 + e], acc);
    gates[((size_t)sg * kRep + r) * 3 + e] = 1.f / (1.f + __expf(-acc));
  }
}

// ---------------------------------------------------------------------------
// Per (s,g,half): selected + sliding attention for 4 heads + gated combine.
// Writes pre-projection activations directly as bf16.
// ---------------------------------------------------------------------------
__global__ __launch_bounds__(256) void sel_sw_kernel(
    const float* __restrict__ q, const float* __restrict__ k,
    const float* __restrict__ v, const float* __restrict__ oc,
    const float* __restrict__ gates,
    const unsigned long long* __restrict__ selmask,
    unsigned short* __restrict__ preb) {
  const int b = blockIdx.x;
  const int half = b & 1;
  const int sg = b >> 1;
  const int s = sg >> 1;
  const int g = sg & 1;
  const int t = threadIdx.x;
  __shared__ float qs[4 * kDH];
  __shared__ float ps[4][513];      // stride 513: bank = (r+tl)%32, conflict-free
  __shared__ int blk[kNSel];
  __shared__ int nblk_sh;
  if (t < 128) {
    const float* src = q + ((size_t)s * kH + g * kRep + half * 4) * kDH;
    reinterpret_cast<float4*>(qs)[t] = reinterpret_cast<const float4*>(src)[t];
  }
  if (t == 0) {
    unsigned long long mask = selmask[sg];
    int mcur = s >> 5;
    int n = 0;
    for (int m = 0; m <= mcur; ++m)
      if ((mask >> m) & 1ull) blk[n++] = m;
    nblk_sh = n;
  }
  __syncthreads();
  const int ns = nblk_sh * kLP;
  // ---- selected scores ----
  for (int task = t; task < 4 * ns; task += 256) {
    int r = task & 3;
    int tl = task >> 2;
    int tok = blk[tl >> 5] * kLP + (tl & 31);
    float sc = -INFINITY;
    if (tok <= s) {
      const float* kr = k + ((size_t)tok * kG + g) * kDH;
      const float* qr = qs + r * kDH;
      float acc = 0.f;
      for (int d = 0; d < kDH; d += 4) {
        float4 qv = *reinterpret_cast<const float4*>(&qr[d]);
        float4 kv = *reinterpret_cast<const float4*>(&kr[d]);
        acc = fmaf(qv.x, kv.x, acc);
        acc = fmaf(qv.y, kv.y, acc);
        acc = fmaf(qv.z, kv.z, acc);
        acc = fmaf(qv.w, kv.w, acc);
      }
      sc = acc * kScale;
    }
    ps[r][tl] = sc;
  }
  __syncthreads();
  // softmax: one 64-lane wave per head
  {
    int r = t >> 6;
    int lane = t & 63;
    float m = -INFINITY;
    for (int tl = lane; tl < ns; tl += 64) m = fmaxf(m, ps[r][tl]);
#pragma unroll
    for (int o = 32; o > 0; o >>= 1) m = fmaxf(m, __shfl_xor(m, o));
    float sum = 0.f;
    for (int tl = lane; tl < ns; tl += 64) {
      float e = __expf(ps[r][tl] - m);
      ps[r][tl] = e;
      sum += e;
    }
#pragma unroll
    for (int o = 32; o > 0; o >>= 1) sum += __shfl_xor(sum, o);
    float inv = 1.f / sum;
    for (int tl = lane; tl < ns; tl += 64) ps[r][tl] *= inv;
  }
  __syncthreads();
  float osel[2], osw[2];
#pragma unroll
  for (int u = 0; u < 2; ++u) {
    int ti = t + u * 256;
    int r = ti >> 7;
    int d = ti & 127;
    float acc = 0.f;
    for (int tl = 0; tl < ns; ++tl) {
      int tok = blk[tl >> 5] * kLP + (tl & 31);
      acc = fmaf(ps[r][tl], v[((size_t)tok * kG + g) * kDH + d], acc);
    }
    osel[u] = acc;
  }
  __syncthreads();
  // ---- sliding window ----
  int t0 = s - (kW - 1);
  if (t0 < 0) t0 = 0;
  const int nt = s - t0 + 1;
  for (int task = t; task < 4 * nt; task += 256) {
    int r = task & 3;
    int tl = task >> 2;
    int tok = t0 + tl;
    const float* kr = k + ((size_t)tok * kG + g) * kDH;
    const float* qr = qs + r * kDH;
    float acc = 0.f;
    for (int d = 0; d < kDH; d += 4) {
      float4 qv = *reinterpret_cast<const float4*>(&qr[d]);
      float4 kv = *reinterpret_cast<const float4*>(&kr[d]);
      acc = fmaf(qv.x, kv.x, acc);
      acc = fmaf(qv.y, kv.y, acc);
      acc = fmaf(qv.z, kv.z, acc);
      acc = fmaf(qv.w, kv.w, acc);
    }
    ps[r][tl] = acc * kScale;
  }
  __syncthreads();
  {
    int r = t >> 6;
    int lane = t & 63;
    float m = -INFINITY;
    for (int tl = lane; tl < nt; tl += 64) m = fmaxf(m, ps[r][tl]);
#pragma unroll
    for (int o = 32; o > 0; o >>= 1) m = fmaxf(m, __shfl_xor(m, o));
    float sum = 0.f;
    for (int tl = lane; tl < nt; tl += 64) {
      float e = __expf(ps[r][tl] - m);
      ps[r][tl] = e;
      sum += e;
    }
#pragma unroll
    for (int o = 32; o > 0; o >>= 1) sum += __shfl_xor(sum, o);
    float inv = 1.f / sum;
    for (int tl = lane; tl < nt; tl += 64) ps[r][tl] *= inv;
  }
  __syncthreads();
#pragma unroll
  for (int u = 0; u < 2; ++u) {
    int ti = t + u * 256;
    int r = ti >> 7;
    int d = ti & 127;
    float acc = 0.f;
    for (int tl = 0; tl < nt; ++tl)
      acc = fmaf(ps[r][tl], v[((size_t)(t0 + tl) * kG + g) * kDH + d], acc);
    osw[u] = acc;
  }
  // ---- combine with gates + o_cmp, write bf16 ----
#pragma unroll
  for (int u = 0; u < 2; ++u) {
    int ti = t + u * 256;
    int r = ti >> 7;
    int d = ti & 127;
    const float* gg = gates + ((size_t)sg * kRep + half * 4 + r) * 3;
    size_t off = ((size_t)s * kH + g * kRep + half * 4 + r) * kDH + d;
    float val = gg[0] * oc[off] + gg[1] * osel[u] + gg[2] * osw[u];
    preb[off] = f2bf(val);
  }
}

// ---------------------------------------------------------------------------
extern "C" void kernel_launch(void* const* d_in, const int* in_sizes, int n_in,
                              void* d_out, int out_size, void* d_ws, size_t ws_size,
                              hipStream_t stream) {
  (void)in_sizes; (void)n_in; (void)out_size; (void)ws_size;
  const float* x  = (const float*)d_in[0];
  const float* fc = (const float*)d_in[1];
  const float* fs = (const float*)d_in[2];
  const float* wq = (const float*)d_in[3];
  const float* wk = (const float*)d_in[4];
  const float* wv = (const float*)d_in[5];
  const float* wo = (const float*)d_in[6];
  const float* wg = (const float*)d_in[7];
  float* out = (float*)d_out;

  // workspace carve-up (f32 then bf16 regions; ~71 MB total)
  float* q    = (float*)d_ws;                    // 4194304
  float* kbuf = q + kS * kH * kDH;               // 524288
  float* vbuf = kbuf + kS * kG * kDH;            // 524288
  float* kc   = vbuf + kS * kG * kDH;            // 32512
  float* vc   = kc + kJ * kG * kDH;              // 32512
  float* oc   = vc + kJ * kG * kDH;              // 4194304
  float* gts  = oc + kS * kH * kDH;              // 98304
  unsigned long long* selmask = (unsigned long long*)(gts + kS * kG * kRep * 3); // 4096
  unsigned short* xb   = (unsigned short*)(selmask + kS * kG);
  unsigned short* wqT  = xb + kS * kDim;         // [2048][2048]
  unsigned short* wkT  = wqT + (kH * kDH) * kDim;  // [256][2048]
  unsigned short* wvT  = wkT + (kG * kDH) * kDim;  // [256][2048]
  unsigned short* woT  = wvT + (kG * kDH) * kDim;  // [2048][2048]
  unsigned short* preb = woT + kDim * (kH * kDH);  // [2048][2048]

  dim3 blk256(256);
  // casts / transposes to bf16
  cast_bf16_kernel<<<kS * kDim / 4 / 256, blk256, 0, stream>>>(x, xb, kS * kDim / 4);
  transpose_cast_kernel<<<dim3((kH * kDH) / 32, kDim / 32), blk256, 0, stream>>>(wq, wqT, kDim, kH * kDH);
  transpose_cast_kernel<<<dim3((kG * kDH) / 32, kDim / 32), blk256, 0, stream>>>(wk, wkT, kDim, kG * kDH);
  transpose_cast_kernel<<<dim3((kG * kDH) / 32, kDim / 32), blk256, 0, stream>>>(wv, wvT, kDim, kG * kDH);
  transpose_cast_kernel<<<dim3(kDim / 32, (kH * kDH) / 32), blk256, 0, stream>>>(wo, woT, kH * kDH, kDim);
  // projections (bf16 MFMA)
  gemm_bf16_kernel<<<dim3(16, 16), blk256, 0, stream>>>(xb, wqT, q, kS, kH * kDH, kDim);
  gemm_bf16_kernel<<<dim3(2, 16), blk256, 0, stream>>>(xb, wkT, kbuf, kS, kG * kDH, kDim);
  gemm_bf16_kernel<<<dim3(2, 16), blk256, 0, stream>>>(xb, wvT, vbuf, kS, kG * kDH, kDim);
  // rope on q and k
  rope_kernel<<<8192, blk256, 0, stream>>>(q, fc, fs, kH, kS * kH * 64);
  rope_kernel<<<1024, blk256, 0, stream>>>(kbuf, fc, fs, kG, kS * kG * 64);
  // compression pooling
  pool_kernel<<<128, blk256, 0, stream>>>(kbuf, vbuf, kc, vc);
  // compressed attention + importance + top-k + gates (f32)
  cmp_attn_kernel<<<kS * kG, blk256, 0, stream>>>(q, kc, vc, wg, oc, gts, selmask);
  // selected + sliding attention + gated combine -> bf16 activations
  sel_sw_kernel<<<kS * kG * 2, blk256, 0, stream>>>(q, kbuf, vbuf, oc, gts, selmask, preb);
  // output projection (bf16 MFMA)
  gemm_bf16_kernel<<<dim3(16, 16), blk256, 0, stream>>>(preb, woT, out, kS, kDim, kH * kDH);
}

// Round 4
// 616.404 us; speedup vs baseline: 5.3035x; 3.7270x over previous
//
#include <hip/hip_runtime.h>
#include <cstddef>
#include <cstdint>
#include <math.h>

// Problem constants (B=1)
#define kS    2048
#define kDim  2048
#define kH    16
#define kG    2
#define kDH   128
#define kRep  8     // H / G
#define kL    32    // compression window
#define kDstr 16    // compression stride
#define kLP   32    // selection block
#define kNSel 16
#define kW    256   // sliding window
#define kJ    127   // (S - L)/D + 1
#define kNB   64    // S / LP
#define kScale 0.08838834764831845f

typedef __attribute__((ext_vector_type(4))) float f32x4;
typedef __attribute__((ext_vector_type(8))) __bf16 bf16x8;
typedef __attribute__((ext_vector_type(4))) __bf16 bf16x4;

__device__ __forceinline__ unsigned short f2bf(float f) {
  unsigned u = __float_as_uint(f);
  u += 0x7fff + ((u >> 16) & 1);   // RNE (finite values only)
  return (unsigned short)(u >> 16);
}

#define GLDS16(src, dst)                                                     \
  __builtin_amdgcn_global_load_lds(                                          \
      (const __attribute__((address_space(1))) unsigned int*)(src),          \
      (__attribute__((address_space(3))) unsigned int*)(dst), 16, 0, 0)

// ---------------------------------------------------------------------------
// f32 -> bf16 cast (vectorized, n4 = n/4)
// ---------------------------------------------------------------------------
__global__ void cast_bf16_kernel(const float* __restrict__ in,
                                 unsigned short* __restrict__ out, int n4) {
  int i = blockIdx.x * blockDim.x + threadIdx.x;
  if (i >= n4) return;
  float4 v = reinterpret_cast<const float4*>(in)[i];
  ushort4 o;
  o.x = f2bf(v.x); o.y = f2bf(v.y); o.z = f2bf(v.z); o.w = f2bf(v.w);
  reinterpret_cast<ushort4*>(out)[i] = o;
}

// ---------------------------------------------------------------------------
// transpose + cast: in[rows][cols] f32 -> out[cols][rows] bf16
// ---------------------------------------------------------------------------
__global__ __launch_bounds__(256) void transpose_cast_kernel(
    const float* __restrict__ in, unsigned short* __restrict__ out,
    int rows, int cols) {
  __shared__ float tile[32][33];
  const int bx = blockIdx.x * 32;   // col
  const int by = blockIdx.y * 32;   // row
  const int tx = threadIdx.x & 31;
  const int ty = threadIdx.x >> 5;
#pragma unroll
  for (int i = 0; i < 32; i += 8)
    tile[ty + i][tx] = in[(size_t)(by + ty + i) * cols + bx + tx];
  __syncthreads();
#pragma unroll
  for (int i = 0; i < 32; i += 8)
    out[(size_t)(bx + ty + i) * rows + by + tx] = f2bf(tile[tx][ty + i]);
}

// ---------------------------------------------------------------------------
// bf16 MFMA GEMM (m97 structure): C[M][N] f32 = A[M][K] x Bt[N][K]^T
// ---------------------------------------------------------------------------
__global__ __launch_bounds__(256) void gemm_bf16_kernel(
    const unsigned short* __restrict__ A,   // [M][K] bf16 bits
    const unsigned short* __restrict__ Bt,  // [N][K] bf16 bits
    float* __restrict__ C, int M, int N, int K) {
  __shared__ __align__(16) unsigned short As[128 * 32];
  __shared__ __align__(16) unsigned short Bs[128 * 32];
  const int t = threadIdx.x;
  const int lane = t & 63;
  const int wid = t >> 6;
  const int wr = wid >> 1, wc = wid & 1;
  const int lhi = lane >> 4, llo = lane & 15;
  const size_t row0 = (size_t)blockIdx.y * 128;
  const size_t col0 = (size_t)blockIdx.x * 128;

  f32x4 acc[4][4];
#pragma unroll
  for (int m = 0; m < 4; ++m)
#pragma unroll
    for (int n = 0; n < 4; ++n) acc[m][n] = f32x4{0.f, 0.f, 0.f, 0.f};

  const int e0 = t * 8;
  const int e1 = 2048 + t * 8;
  const int r0 = e0 >> 5, kk0 = e0 & 31;
  const int r1 = e1 >> 5, kk1 = e1 & 31;

  for (int k0 = 0; k0 < K; k0 += 32) {
    GLDS16(A + (row0 + r0) * (size_t)K + k0 + kk0, As + e0);
    GLDS16(A + (row0 + r1) * (size_t)K + k0 + kk1, As + e1);
    GLDS16(Bt + (col0 + r0) * (size_t)K + k0 + kk0, Bs + e0);
    GLDS16(Bt + (col0 + r1) * (size_t)K + k0 + kk1, Bs + e1);
    __syncthreads();
    bf16x8 af[4], bfr[4];
#pragma unroll
    for (int m = 0; m < 4; ++m)
      af[m] = *reinterpret_cast<const bf16x8*>(&As[(wr * 64 + m * 16 + llo) * 32 + lhi * 8]);
#pragma unroll
    for (int n = 0; n < 4; ++n)
      bfr[n] = *reinterpret_cast<const bf16x8*>(&Bs[(wc * 64 + n * 16 + llo) * 32 + lhi * 8]);
#pragma unroll
    for (int m = 0; m < 4; ++m)
#pragma unroll
      for (int n = 0; n < 4; ++n)
        acc[m][n] = __builtin_amdgcn_mfma_f32_16x16x32_bf16(af[m], bfr[n], acc[m][n], 0, 0, 0);
    __syncthreads();
  }
#pragma unroll
  for (int m = 0; m < 4; ++m)
#pragma unroll
    for (int n = 0; n < 4; ++n)
#pragma unroll
      for (int j = 0; j < 4; ++j) {
        size_t r = row0 + wr * 64 + m * 16 + lhi * 4 + j;
        size_t c = col0 + wc * 64 + n * 16 + llo;
        C[r * (size_t)N + c] = acc[m][n][j];
      }
}

// ---------------------------------------------------------------------------
// RoPE (interleaved pairs), in place. t: (S, nheads, DH)
// ---------------------------------------------------------------------------
__global__ void rope_kernel(float* __restrict__ tb, const float* __restrict__ fc,
                            const float* __restrict__ fsn, int nheads, int total) {
  int idx = blockIdx.x * blockDim.x + threadIdx.x;
  if (idx >= total) return;
  int i = idx & 63;
  int h = (idx >> 6) % nheads;
  int s = idx / (64 * nheads);
  float c = fc[s * 64 + i];
  float sn = fsn[s * 64 + i];
  float* p = tb + ((size_t)s * nheads + h) * kDH + 2 * i;
  float x0 = p[0], x1 = p[1];
  p[0] = x0 * c - x1 * sn;
  p[1] = x0 * sn + x1 * c;
}

// ---------------------------------------------------------------------------
// Compression mean-pool
// ---------------------------------------------------------------------------
__global__ void pool_kernel(const float* __restrict__ k, const float* __restrict__ v,
                            float* __restrict__ kc, float* __restrict__ vc) {
  int idx = blockIdx.x * blockDim.x + threadIdx.x;
  if (idx >= kJ * kG * kDH) return;
  int d = idx & 127;
  int g = (idx >> 7) & 1;
  int j = idx >> 8;
  float sk = 0.f, sv = 0.f;
  for (int l = 0; l < kL; ++l) {
    size_t off = ((size_t)(j * kDstr + l) * kG + g) * kDH + d;
    sk += k[off];
    sv += v[off];
  }
  kc[idx] = sk * (1.f / 32.f);
  vc[idx] = sv * (1.f / 32.f);
}

// ---------------------------------------------------------------------------
// Per (s,g): compressed attention, importance, top-k, gates (exact f32 path)
// ---------------------------------------------------------------------------
__global__ __launch_bounds__(256) void cmp_attn_kernel(
    const float* __restrict__ q, const float* __restrict__ kc,
    const float* __restrict__ vc, const float* __restrict__ wg,
    float* __restrict__ oc, float* __restrict__ gates,
    unsigned long long* __restrict__ selmask) {
  const int sg = blockIdx.x;
  const int s = sg >> 1;
  const int g = sg & 1;
  const int t = threadIdx.x;
  __shared__ float qs[kRep * kDH];
  __shared__ float p[kRep][kJ + 1];
  __shared__ float imp[kNB];
  {
    const float* src = q + ((size_t)s * kH + g * kRep) * kDH;
    *reinterpret_cast<float4*>(&qs[t * 4]) =
        *reinterpret_cast<const float4*>(&src[t * 4]);
  }
  __syncthreads();
  const int jmax = (s >= kL - 1) ? ((s - (kL - 1)) >> 4) : -1;
  for (int task = t; task < kRep * kJ; task += 256) {
    int r = task & 7;
    int j = task >> 3;
    float sc = -INFINITY;
    if (j <= jmax) {
      const float* kr = kc + ((size_t)j * kG + g) * kDH;
      const float* qr = qs + r * kDH;
      float acc = 0.f;
      for (int d = 0; d < kDH; d += 4) {
        float4 qv = *reinterpret_cast<const float4*>(&qr[d]);
        float4 kv = *reinterpret_cast<const float4*>(&kr[d]);
        acc = fmaf(qv.x, kv.x, acc);
        acc = fmaf(qv.y, kv.y, acc);
        acc = fmaf(qv.z, kv.z, acc);
        acc = fmaf(qv.w, kv.w, acc);
      }
      sc = acc * kScale;
    }
    p[r][j] = sc;
  }
  __syncthreads();
  if (t < kRep) {
    int r = t;
    if (jmax < 0) {
      for (int j = 0; j < kJ; ++j) p[r][j] = 0.f;
    } else {
      float m = -INFINITY;
      for (int j = 0; j <= jmax; ++j) m = fmaxf(m, p[r][j]);
      float sum = 0.f;
      for (int j = 0; j <= jmax; ++j) {
        float e = __expf(p[r][j] - m);
        p[r][j] = e;
        sum += e;
      }
      float inv = 1.f / sum;
      for (int j = 0; j <= jmax; ++j) p[r][j] *= inv;
      for (int j = jmax + 1; j < kJ; ++j) p[r][j] = 0.f;
    }
  }
  __syncthreads();
  for (int task = t; task < kRep * kDH; task += 256) {
    int r = task >> 7;
    int d = task & 127;
    float acc = 0.f;
    for (int j = 0; j <= jmax; ++j)
      acc = fmaf(p[r][j], vc[((size_t)j * kG + g) * kDH + d], acc);
    oc[((size_t)s * kH + g * kRep + r) * kDH + d] = acc;
  }
  const int mcur = s >> 5;
  if (t < kNB) {
    int m = t;
    float im;
    if (m > mcur) {
      im = -INFINITY;
    } else {
      im = 0.f;
      for (int r = 0; r < kRep; ++r) {
        float sump = p[r][2 * m];
        if (2 * m - 1 >= 0) sump += p[r][2 * m - 1];
        if (2 * m + 1 < kJ) sump += p[r][2 * m + 1];
        im += sump;
      }
      if (m == 0) im += 1e9f;
      if (m == mcur) im += 1e9f;
    }
    imp[m] = im;
  }
  __syncthreads();
  if (t == 0) {
    unsigned long long mask = 0ull;
    for (int it = 0; it < kNSel; ++it) {
      float best = -INFINITY;
      int bi = -1;
      for (int m = 0; m < kNB; ++m) {
        if ((mask >> m) & 1ull) continue;
        float v2 = imp[m];
        if (bi < 0 || v2 > best) { best = v2; bi = m; }
      }
      mask |= (1ull << bi);
    }
    selmask[sg] = mask;
  }
  if (t < kRep * 3) {
    int r = t / 3;
    int e = t - r * 3;
    const float* qr = qs + r * kDH;
    float acc = 0.f;
    for (int d = 0; d < kDH; ++d) acc = fmaf(qr[d], wg[d * 3 + e], acc);
    gates[((size_t)sg * kRep + r) * 3 + e] = 1.f / (1.f + __expf(-acc));
  }
}

// ---------------------------------------------------------------------------
// Fused MFMA flash attention: selected + sliding, per (g, 16-query tile).
// 128 rows = 16 queries x 8 heads (GQA shares K/V). S^T via mfma(K,Q) ->
// softmax state lane-local (qrow = lane&15). PV: O^T = mfma(V^T, P) with
// V pre-transposed in GLOBAL memory (staged linearly) and P re-read from a
// per-wave LDS buffer in natural token order. No swizzle, no inline asm.
// ---------------------------------------------------------------------------
__device__ __forceinline__ void stage_kv(
    const unsigned short* __restrict__ kb, const unsigned short* __restrict__ vT,
    int g, int tb, unsigned short* Ksb, unsigned short* VTb, int t) {
  // K tile [32 tok][128 d], linear
#pragma unroll
  for (int i = 0; i < 2; ++i) {
    int e = i * 2048 + t * 8;
    int row = e >> 7;          // token within tile
    int c = e & 127;           // d element
    GLDS16(kb + (size_t)(tb + row) * 256 + g * 128 + c, Ksb + e);
  }
  // V^T tile [128 d][32 tok], linear (vT is [g*128+d][2048 tok] in global)
#pragma unroll
  for (int i = 0; i < 2; ++i) {
    int e = i * 2048 + t * 8;
    int d = e >> 5;            // d within tile
    int tok0 = e & 31;         // token element
    GLDS16(vT + (size_t)(g * 128 + d) * 2048 + tb + tok0, VTb + e);
  }
}

template <int MODE>  // 0 = selected, 1 = sliding window
__device__ __forceinline__ void attn_tile(
    const unsigned short* Qs, const unsigned short* Ksb,
    const unsigned short* VTb, __bf16* Psw,
    int tb, unsigned selw, int wv, int lo, int hi, int s0,
    f32x4 (&O)[8][2], float (&mst)[2], float (&lst)[2]) {
  // ---- QK^T (S^T: tok = frag-row, query-row = lane&15) ----
  f32x4 S[2][2];
#pragma unroll
  for (int tf = 0; tf < 2; ++tf)
#pragma unroll
    for (int rf = 0; rf < 2; ++rf) S[tf][rf] = f32x4{0.f, 0.f, 0.f, 0.f};
#pragma unroll
  for (int ds = 0; ds < 4; ++ds) {
    bf16x8 a[2], b[2];
#pragma unroll
    for (int tf = 0; tf < 2; ++tf)
      a[tf] = *reinterpret_cast<const bf16x8*>(
          &Ksb[(tf * 16 + lo) * 128 + ds * 32 + hi * 8]);
#pragma unroll
    for (int rf = 0; rf < 2; ++rf)
      b[rf] = *reinterpret_cast<const bf16x8*>(
          &Qs[(wv * 32 + rf * 16 + lo) * 128 + ds * 32 + hi * 8]);
#pragma unroll
    for (int tf = 0; tf < 2; ++tf)
#pragma unroll
      for (int rf = 0; rf < 2; ++rf)
        S[tf][rf] = __builtin_amdgcn_mfma_f32_16x16x32_bf16(a[tf], b[rf], S[tf][rf], 0, 0, 0);
  }
  // ---- mask + online softmax (state lane-local: qrow = lane&15) ----
#pragma unroll
  for (int rf = 0; rf < 2; ++rf) {
    int qloc = wv * 4 + rf * 2 + (lo >> 3);
    int s_row = s0 + qloc;
    bool selq = (MODE == 1) ? true : (((selw >> qloc) & 1u) != 0);
#pragma unroll
    for (int tf = 0; tf < 2; ++tf)
#pragma unroll
      for (int j = 0; j < 4; ++j) {
        int tok = tb + tf * 16 + hi * 4 + j;
        bool ok = selq && (tok <= s_row) && (MODE == 0 || tok > s_row - kW);
        S[tf][rf][j] = ok ? S[tf][rf][j] * kScale : -1e30f;
      }
    float pm = S[0][rf][0];
#pragma unroll
    for (int tf = 0; tf < 2; ++tf)
#pragma unroll
      for (int j = 0; j < 4; ++j) pm = fmaxf(pm, S[tf][rf][j]);
    pm = fmaxf(pm, __shfl_xor(pm, 16));
    pm = fmaxf(pm, __shfl_xor(pm, 32));
    float mo = mst[rf];
    if (__any(pm > mo)) {
      float mn = fmaxf(mo, pm);
      float f = __expf(mo - mn);
#pragma unroll
      for (int df = 0; df < 8; ++df)
#pragma unroll
        for (int j = 0; j < 4; ++j) O[df][rf][j] *= f;
      lst[rf] *= f;
      mst[rf] = mn;
    }
    float lacc = 0.f;
#pragma unroll
    for (int tf = 0; tf < 2; ++tf) {
      bf16x4 pk;
#pragma unroll
      for (int j = 0; j < 4; ++j) {
        float e = __expf(S[tf][rf][j] - mst[rf]);
        lacc += e;
        pk[j] = (__bf16)e;
      }
      // P stored [qrow][tok] per wave: row = rf*16+lo, cols tf*16+hi*4..+4
      *reinterpret_cast<bf16x4*>(&Psw[(rf * 16 + lo) * 32 + tf * 16 + hi * 4]) = pk;
    }
    lst[rf] += lacc;
  }
  // ---- PV: O^T[d][qrow] += V^T[d][tok] x P^T[tok][qrow] ----
  // a-frag: V^T rows (d = df*16 + lane&15), k = toks (lane>>4)*8..+8 (natural)
  // b-frag: P rows (qrow = rf*16 + lane&15), k = toks (lane>>4)*8..+8 (natural)
  bf16x8 pfrag[2];
#pragma unroll
  for (int rf = 0; rf < 2; ++rf)
    pfrag[rf] = *reinterpret_cast<const bf16x8*>(&Psw[(rf * 16 + lo) * 32 + hi * 8]);
#pragma unroll
  for (int df = 0; df < 8; ++df) {
    bf16x8 vfrag = *reinterpret_cast<const bf16x8*>(&VTb[(df * 16 + lo) * 32 + hi * 8]);
#pragma unroll
    for (int rf = 0; rf < 2; ++rf)
      O[df][rf] = __builtin_amdgcn_mfma_f32_16x16x32_bf16(vfrag, pfrag[rf], O[df][rf], 0, 0, 0);
  }
}

__global__ __launch_bounds__(256) void fused_attn_kernel(
    const unsigned short* __restrict__ qb, const unsigned short* __restrict__ kb,
    const unsigned short* __restrict__ vT, const float* __restrict__ ocp,
    const float* __restrict__ gts,
    const unsigned long long* __restrict__ selmask,
    unsigned short* __restrict__ preb) {
  __shared__ __align__(16) unsigned short Qs[16384];      // [128 qrow][128 d]
  __shared__ __align__(16) unsigned short Ks[2][4096];    // [32 tok][128 d]
  __shared__ __align__(16) unsigned short VTs[2][4096];   // [128 d][32 tok]
  __shared__ __align__(16) __bf16 Ps[4][1024];            // per-wave [32 qrow][32 tok]
  __shared__ unsigned long long qm[16];
  __shared__ unsigned int selbits[kNB];
  __shared__ unsigned char blist[kNB];
  __shared__ int nsel_sh;

  const int g = blockIdx.x & 1;
  const int qt = blockIdx.x >> 1;
  const int s0 = qt * 16;
  const int t = threadIdx.x;
  const int lane = t & 63;
  const int wv = t >> 6;
  const int lo = lane & 15, hi = lane >> 4;

  // stage Q (128 rows = query*8 + head_local, linear)
#pragma unroll
  for (int i = 0; i < 8; ++i) {
    int e = i * 2048 + t * 8;
    int row = e >> 7;
    int c = e & 127;
    GLDS16(qb + ((size_t)(s0 + (row >> 3)) * 16 + g * 8 + (row & 7)) * 128 + c,
           Qs + e);
  }
  // per-query causal-masked selection masks
  if (t < 16) {
    int mcur = s0 >> 5;
    unsigned long long mm = selmask[(size_t)(s0 + t) * 2 + g];
    mm &= ((2ull << mcur) - 1ull);
    qm[t] = mm;
  }
  __syncthreads();
  if (t < kNB) {
    unsigned b = 0;
    for (int ql = 0; ql < 16; ++ql)
      b |= (unsigned)((qm[ql] >> t) & 1ull) << ql;
    selbits[t] = b;
  }
  if (t == 0) {
    unsigned long long u = 0;
    for (int ql = 0; ql < 16; ++ql) u |= qm[ql];
    int n = 0;
    for (int m = 0; m < kNB; ++m)
      if ((u >> m) & 1ull) blist[n++] = (unsigned char)m;
    nsel_sh = n;
  }
  __syncthreads();

  __bf16* Psw = &Ps[wv][0];

  f32x4 O1[8][2], O2[8][2];
  float mst[2], lst[2];
#pragma unroll
  for (int df = 0; df < 8; ++df)
#pragma unroll
    for (int rf = 0; rf < 2; ++rf) O1[df][rf] = f32x4{0.f, 0.f, 0.f, 0.f};
  mst[0] = mst[1] = -INFINITY;
  lst[0] = lst[1] = 0.f;

  // ---- PASS 1: selected blocks (union + per-query bits) ----
  const int nsel = nsel_sh;
  stage_kv(kb, vT, g, (int)blist[0] * 32, Ks[0], VTs[0], t);
  for (int i = 0; i < nsel; ++i) {
    __syncthreads();   // drains stage(i) loads; prev compute already done
    if (i + 1 < nsel)
      stage_kv(kb, vT, g, (int)blist[i + 1] * 32, Ks[(i + 1) & 1], VTs[(i + 1) & 1], t);
    int b = blist[i];
    attn_tile<0>(Qs, Ks[i & 1], VTs[i & 1], Psw, b * 32, selbits[b], wv, lo, hi, s0,
                 O1, mst, lst);
  }
  // finalize pass 1: scale by g1 / l_sel (lane-local rows)
  float g0v[2], g2v[2];
#pragma unroll
  for (int rf = 0; rf < 2; ++rf) {
    int row = wv * 32 + rf * 16 + lo;
    int s_row = s0 + (row >> 3);
    int r = row & 7;
    const float* gp = gts + ((size_t)(s_row * 2 + g) * 8 + r) * 3;
    g0v[rf] = gp[0];
    g2v[rf] = gp[2];
    float lt = lst[rf];
    lt += __shfl_xor(lt, 16);
    lt += __shfl_xor(lt, 32);
    float f = gp[1] / lt;
#pragma unroll
    for (int df = 0; df < 8; ++df)
#pragma unroll
      for (int j = 0; j < 4; ++j) O1[df][rf][j] *= f;
    mst[rf] = -INFINITY;
    lst[rf] = 0.f;
  }
#pragma unroll
  for (int df = 0; df < 8; ++df)
#pragma unroll
    for (int rf = 0; rf < 2; ++rf) O2[df][rf] = f32x4{0.f, 0.f, 0.f, 0.f};

  // ---- PASS 2: sliding window, tiles DESCENDING (first tile valid/row) ----
  const int hi_t = s0 >> 5;
  const int lo_t = (s0 > 255) ? ((s0 - 255) >> 5) : 0;
  const int nsw = hi_t - lo_t + 1;
  __syncthreads();   // last sel compute done before buffer reuse
  stage_kv(kb, vT, g, hi_t * 32, Ks[0], VTs[0], t);
  for (int ii = 0; ii < nsw; ++ii) {
    __syncthreads();
    if (ii + 1 < nsw)
      stage_kv(kb, vT, g, (hi_t - ii - 1) * 32, Ks[(ii + 1) & 1], VTs[(ii + 1) & 1], t);
    attn_tile<1>(Qs, Ks[ii & 1], VTs[ii & 1], Psw, (hi_t - ii) * 32, 0u, wv, lo, hi, s0,
                 O2, mst, lst);
  }
  // ---- combine: g0*o_cmp + g1*o_sel + g2*o_sw -> bf16 ----
#pragma unroll
  for (int rf = 0; rf < 2; ++rf) {
    int row = wv * 32 + rf * 16 + lo;
    int s_row = s0 + (row >> 3);
    int r = row & 7;
    float lt = lst[rf];
    lt += __shfl_xor(lt, 16);
    lt += __shfl_xor(lt, 32);
    float f2 = g2v[rf] / lt;
    size_t base = ((size_t)s_row * 16 + g * 8 + r) * 128;
#pragma unroll
    for (int df = 0; df < 8; ++df) {
      int d0 = df * 16 + hi * 4;
      float4 ocv = *reinterpret_cast<const float4*>(&ocp[base + d0]);
      ushort4 w;
      w.x = f2bf(g0v[rf] * ocv.x + O1[df][rf][0] + f2 * O2[df][rf][0]);
      w.y = f2bf(g0v[rf] * ocv.y + O1[df][rf][1] + f2 * O2[df][rf][1]);
      w.z = f2bf(g0v[rf] * ocv.z + O1[df][rf][2] + f2 * O2[df][rf][2]);
      w.w = f2bf(g0v[rf] * ocv.w + O1[df][rf][3] + f2 * O2[df][rf][3]);
      *reinterpret_cast<ushort4*>(&preb[base + d0]) = w;
    }
  }
}

// ---------------------------------------------------------------------------
extern "C" void kernel_launch(void* const* d_in, const int* in_sizes, int n_in,
                              void* d_out, int out_size, void* d_ws, size_t ws_size,
                              hipStream_t stream) {
  (void)in_sizes; (void)n_in; (void)out_size; (void)ws_size;
  const float* x  = (const float*)d_in[0];
  const float* fc = (const float*)d_in[1];
  const float* fs = (const float*)d_in[2];
  const float* wq = (const float*)d_in[3];
  const float* wk = (const float*)d_in[4];
  const float* wv = (const float*)d_in[5];
  const float* wo = (const float*)d_in[6];
  const float* wg = (const float*)d_in[7];
  float* out = (float*)d_out;

  float* q    = (float*)d_ws;                    // 4194304 f32
  float* kbuf = q + kS * kH * kDH;               // 524288
  float* vbuf = kbuf + kS * kG * kDH;            // 524288
  float* kc   = vbuf + kS * kG * kDH;            // 32512
  float* vc   = kc + kJ * kG * kDH;              // 32512
  float* oc   = vc + kJ * kG * kDH;              // 4194304
  float* gts  = oc + kS * kH * kDH;              // 98304
  unsigned long long* selmask = (unsigned long long*)(gts + kS * kG * kRep * 3); // 4096
  unsigned short* xb   = (unsigned short*)(selmask + kS * kG);
  unsigned short* wqT  = xb + kS * kDim;           // [2048][2048]
  unsigned short* wkT  = wqT + (kH * kDH) * kDim;  // [256][2048]
  unsigned short* wvT  = wkT + (kG * kDH) * kDim;  // [256][2048]
  unsigned short* woT  = wvT + (kG * kDH) * kDim;  // [2048][2048]
  unsigned short* preb = woT + kDim * (kH * kDH);  // [2048][2048]
  unsigned short* kb   = preb + kS * kDim;         // [2048 tok][2 g][128 d]
  unsigned short* vT   = kb + kS * kG * kDH;       // [2 g * 128 d][2048 tok]
  unsigned short* qbuf = xb;   // alias: xb dead after projection GEMMs

  dim3 blk256(256);
  cast_bf16_kernel<<<kS * kDim / 4 / 256, blk256, 0, stream>>>(x, xb, kS * kDim / 4);
  transpose_cast_kernel<<<dim3((kH * kDH) / 32, kDim / 32), blk256, 0, stream>>>(wq, wqT, kDim, kH * kDH);
  transpose_cast_kernel<<<dim3((kG * kDH) / 32, kDim / 32), blk256, 0, stream>>>(wk, wkT, kDim, kG * kDH);
  transpose_cast_kernel<<<dim3((kG * kDH) / 32, kDim / 32), blk256, 0, stream>>>(wv, wvT, kDim, kG * kDH);
  transpose_cast_kernel<<<dim3(kDim / 32, (kH * kDH) / 32), blk256, 0, stream>>>(wo, woT, kH * kDH, kDim);
  gemm_bf16_kernel<<<dim3(16, 16), blk256, 0, stream>>>(xb, wqT, q, kS, kH * kDH, kDim);
  gemm_bf16_kernel<<<dim3(2, 16), blk256, 0, stream>>>(xb, wkT, kbuf, kS, kG * kDH, kDim);
  gemm_bf16_kernel<<<dim3(2, 16), blk256, 0, stream>>>(xb, wvT, vbuf, kS, kG * kDH, kDim);
  rope_kernel<<<8192, blk256, 0, stream>>>(q, fc, fs, kH, kS * kH * 64);
  rope_kernel<<<1024, blk256, 0, stream>>>(kbuf, fc, fs, kG, kS * kG * 64);
  // bf16 copies for the MFMA attention (xb dead -> qbuf); V transposed in global
  cast_bf16_kernel<<<kS * kH * kDH / 4 / 256, blk256, 0, stream>>>(q, qbuf, kS * kH * kDH / 4);
  cast_bf16_kernel<<<kS * kG * kDH / 4 / 256, blk256, 0, stream>>>(kbuf, kb, kS * kG * kDH / 4);
  transpose_cast_kernel<<<dim3(kG * kDH / 32, kS / 32), blk256, 0, stream>>>(vbuf, vT, kS, kG * kDH);
  pool_kernel<<<128, blk256, 0, stream>>>(kbuf, vbuf, kc, vc);
  cmp_attn_kernel<<<kS * kG, blk256, 0, stream>>>(q, kc, vc, wg, oc, gts, selmask);
  fused_attn_kernel<<<kS / 16 * kG, blk256, 0, stream>>>(qbuf, kb, vT, oc, gts, selmask, preb);
  gemm_bf16_kernel<<<dim3(16, 16), blk256, 0, stream>>>(preb, woT, out, kS, kDim, kH * kDH);
}

// Round 5
// 489.060 us; speedup vs baseline: 6.6844x; 1.2604x over previous
//
#include <hip/hip_runtime.h>
#include <cstddef>
#include <cstdint>
#include <math.h>

// Problem constants (B=1)
#define kS    2048
#define kDim  2048
#define kH    16
#define kG    2
#define kDH   128
#define kRep  8     // H / G
#define kL    32    // compression window
#define kDstr 16    // compression stride
#define kLP   32    // selection block
#define kNSel 16
#define kW    256   // sliding window
#define kJ    127   // (S - L)/D + 1
#define kNB   64    // S / LP
#define kScale 0.08838834764831845f
#define kQT   4     // queries per cmp_attn block

typedef __attribute__((ext_vector_type(4))) float f32x4;
typedef __attribute__((ext_vector_type(8))) __bf16 bf16x8;
typedef __attribute__((ext_vector_type(4))) __bf16 bf16x4;

__device__ __forceinline__ unsigned short f2bf(float f) {
  unsigned u = __float_as_uint(f);
  u += 0x7fff + ((u >> 16) & 1);   // RNE (finite values only)
  return (unsigned short)(u >> 16);
}

#define GLDS16(src, dst)                                                     \
  __builtin_amdgcn_global_load_lds(                                          \
      (const __attribute__((address_space(1))) unsigned int*)(src),          \
      (__attribute__((address_space(3))) unsigned int*)(dst), 16, 0, 0)

// ---------------------------------------------------------------------------
// f32 -> bf16 cast (vectorized, n4 = n/4)
// ---------------------------------------------------------------------------
__global__ void cast_bf16_kernel(const float* __restrict__ in,
                                 unsigned short* __restrict__ out, int n4) {
  int i = blockIdx.x * blockDim.x + threadIdx.x;
  if (i >= n4) return;
  float4 v = reinterpret_cast<const float4*>(in)[i];
  ushort4 o;
  o.x = f2bf(v.x); o.y = f2bf(v.y); o.z = f2bf(v.z); o.w = f2bf(v.w);
  reinterpret_cast<ushort4*>(out)[i] = o;
}

// ---------------------------------------------------------------------------
// transpose + cast: in[rows][cols] f32 -> out[cols][rows] bf16
// ---------------------------------------------------------------------------
__global__ __launch_bounds__(256) void transpose_cast_kernel(
    const float* __restrict__ in, unsigned short* __restrict__ out,
    int rows, int cols) {
  __shared__ float tile[32][33];
  const int bx = blockIdx.x * 32;   // col
  const int by = blockIdx.y * 32;   // row
  const int tx = threadIdx.x & 31;
  const int ty = threadIdx.x >> 5;
#pragma unroll
  for (int i = 0; i < 32; i += 8)
    tile[ty + i][tx] = in[(size_t)(by + ty + i) * cols + bx + tx];
  __syncthreads();
#pragma unroll
  for (int i = 0; i < 32; i += 8)
    out[(size_t)(bx + ty + i) * rows + by + tx] = f2bf(tile[tx][ty + i]);
}

// ---------------------------------------------------------------------------
// bf16 MFMA GEMM (m97 structure): C[M][N] f32 = A[M][K] x Bt[N][K]^T
// ---------------------------------------------------------------------------
__global__ __launch_bounds__(256) void gemm_bf16_kernel(
    const unsigned short* __restrict__ A,   // [M][K] bf16 bits
    const unsigned short* __restrict__ Bt,  // [N][K] bf16 bits
    float* __restrict__ C, int M, int N, int K) {
  __shared__ __align__(16) unsigned short As[128 * 32];
  __shared__ __align__(16) unsigned short Bs[128 * 32];
  const int t = threadIdx.x;
  const int lane = t & 63;
  const int wid = t >> 6;
  const int wr = wid >> 1, wc = wid & 1;
  const int lhi = lane >> 4, llo = lane & 15;
  const size_t row0 = (size_t)blockIdx.y * 128;
  const size_t col0 = (size_t)blockIdx.x * 128;

  f32x4 acc[4][4];
#pragma unroll
  for (int m = 0; m < 4; ++m)
#pragma unroll
    for (int n = 0; n < 4; ++n) acc[m][n] = f32x4{0.f, 0.f, 0.f, 0.f};

  const int e0 = t * 8;
  const int e1 = 2048 + t * 8;
  const int r0 = e0 >> 5, kk0 = e0 & 31;
  const int r1 = e1 >> 5, kk1 = e1 & 31;

  for (int k0 = 0; k0 < K; k0 += 32) {
    GLDS16(A + (row0 + r0) * (size_t)K + k0 + kk0, As + e0);
    GLDS16(A + (row0 + r1) * (size_t)K + k0 + kk1, As + e1);
    GLDS16(Bt + (col0 + r0) * (size_t)K + k0 + kk0, Bs + e0);
    GLDS16(Bt + (col0 + r1) * (size_t)K + k0 + kk1, Bs + e1);
    __syncthreads();
    bf16x8 af[4], bfr[4];
#pragma unroll
    for (int m = 0; m < 4; ++m)
      af[m] = *reinterpret_cast<const bf16x8*>(&As[(wr * 64 + m * 16 + llo) * 32 + lhi * 8]);
#pragma unroll
    for (int n = 0; n < 4; ++n)
      bfr[n] = *reinterpret_cast<const bf16x8*>(&Bs[(wc * 64 + n * 16 + llo) * 32 + lhi * 8]);
#pragma unroll
    for (int m = 0; m < 4; ++m)
#pragma unroll
      for (int n = 0; n < 4; ++n)
        acc[m][n] = __builtin_amdgcn_mfma_f32_16x16x32_bf16(af[m], bfr[n], acc[m][n], 0, 0, 0);
    __syncthreads();
  }
#pragma unroll
  for (int m = 0; m < 4; ++m)
#pragma unroll
    for (int n = 0; n < 4; ++n)
#pragma unroll
      for (int j = 0; j < 4; ++j) {
        size_t r = row0 + wr * 64 + m * 16 + lhi * 4 + j;
        size_t c = col0 + wc * 64 + n * 16 + llo;
        C[r * (size_t)N + c] = acc[m][n][j];
      }
}

// ---------------------------------------------------------------------------
// RoPE (interleaved pairs), in place. t: (S, nheads, DH)
// ---------------------------------------------------------------------------
__global__ void rope_kernel(float* __restrict__ tb, const float* __restrict__ fc,
                            const float* __restrict__ fsn, int nheads, int total) {
  int idx = blockIdx.x * blockDim.x + threadIdx.x;
  if (idx >= total) return;
  int i = idx & 63;
  int h = (idx >> 6) % nheads;
  int s = idx / (64 * nheads);
  float c = fc[s * 64 + i];
  float sn = fsn[s * 64 + i];
  float* p = tb + ((size_t)s * nheads + h) * kDH + 2 * i;
  float x0 = p[0], x1 = p[1];
  p[0] = x0 * c - x1 * sn;
  p[1] = x0 * sn + x1 * c;
}

// ---------------------------------------------------------------------------
// Compression mean-pool
// ---------------------------------------------------------------------------
__global__ void pool_kernel(const float* __restrict__ k, const float* __restrict__ v,
                            float* __restrict__ kc, float* __restrict__ vc) {
  int idx = blockIdx.x * blockDim.x + threadIdx.x;
  if (idx >= kJ * kG * kDH) return;
  int d = idx & 127;
  int g = (idx >> 7) & 1;
  int j = idx >> 8;
  float sk = 0.f, sv = 0.f;
  for (int l = 0; l < kL; ++l) {
    size_t off = ((size_t)(j * kDstr + l) * kG + g) * kDH + d;
    sk += k[off];
    sv += v[off];
  }
  kc[idx] = sk * (1.f / 32.f);
  vc[idx] = sv * (1.f / 32.f);
}

// ---------------------------------------------------------------------------
// cmp_attn v2: block = (g, 4 queries) -> M = 32 rows (4q x 8r).
// Two register-tiled f32 mini-GEMMs (scores M x 128j x 128d, PV M x 128d x 128j)
// + wave-parallel softmax + register-only top-k (wave = query, lane = block).
// Selection semantics identical to the serial version (f32, stable ties).
// ---------------------------------------------------------------------------
__global__ __launch_bounds__(256) void cmp_attn_kernel(
    const float* __restrict__ q, const float* __restrict__ kc,
    const float* __restrict__ vc, const float* __restrict__ wg,
    float* __restrict__ oc, float* __restrict__ gates,
    unsigned long long* __restrict__ selmask) {
  __shared__ float qst[128][36];   // [d][row]   (pad 36: 16B-aligned rows)
  __shared__ float pT [128][36];   // [j][row]   raw scores -> probs
  __shared__ float kvt[32][132];   // staging: kct[dd][j] then vct[jj][d]

  const int b = blockIdx.x;
  const int g = b & 1;
  const int s0 = (b >> 1) * kQT;
  const int t = threadIdx.x;
  const int ty = t >> 5;          // 0..7 -> rows ty*4..+3
  const int tx = t & 31;          // cols tx*4..+3

  // ---- stage q transposed: row = qq*8 + r ----
  {
    int row = t >> 3;            // 0..31
    int dl = t & 7;
    const float* src = q + ((size_t)(s0 + (row >> 3)) * kH + g * kRep + (row & 7)) * kDH;
#pragma unroll
    for (int i = 0; i < 16; ++i) {
      int d = dl + i * 8;
      qst[d][row] = src[d];
    }
  }
  __syncthreads();

  // ---- scores: S[row][j] over 4 d-tiles of 32 ----
  float S[4][4];
#pragma unroll
  for (int rr = 0; rr < 4; ++rr)
#pragma unroll
    for (int jj = 0; jj < 4; ++jj) S[rr][jj] = 0.f;

  for (int dt = 0; dt < 4; ++dt) {
    {
      int dd = t & 31;
      int j0 = t >> 5;
#pragma unroll
      for (int i = 0; i < 16; ++i) {
        int j = j0 + i * 8;
        int jc = j < kJ ? j : kJ - 1;
        kvt[dd][j] = kc[((size_t)jc * kG + g) * kDH + dt * 32 + dd];
      }
    }
    __syncthreads();
#pragma unroll
    for (int kk = 0; kk < 32; ++kk) {
      float4 a = *reinterpret_cast<const float4*>(&qst[dt * 32 + kk][ty * 4]);
      float4 bb = *reinterpret_cast<const float4*>(&kvt[kk][tx * 4]);
      float av[4] = {a.x, a.y, a.z, a.w};
      float bv[4] = {bb.x, bb.y, bb.z, bb.w};
#pragma unroll
      for (int rr = 0; rr < 4; ++rr)
#pragma unroll
        for (int jj = 0; jj < 4; ++jj)
          S[rr][jj] = fmaf(av[rr], bv[jj], S[rr][jj]);
    }
    __syncthreads();
  }

  // ---- mask + scale -> pT[j][row] ----
#pragma unroll
  for (int rr = 0; rr < 4; ++rr) {
    int row = ty * 4 + rr;
    int s = s0 + (row >> 3);
    int jmax = (s >= kL - 1) ? ((s - (kL - 1)) >> 4) : -1;
#pragma unroll
    for (int jj = 0; jj < 4; ++jj) {
      int j = tx * 4 + jj;
      pT[j][row] = (j <= jmax && j < kJ) ? S[rr][jj] * kScale : -1e30f;
    }
  }
  __syncthreads();

  // ---- softmax: 8 lanes per row ----
  {
    int row = t >> 3;
    int l = t & 3 * 2 + (t & 7) - (t & 7);  // (kept simple below)
    l = t & 7;
    int s = s0 + (row >> 3);
    if (s < kL - 1) {
#pragma unroll
      for (int i = 0; i < 16; ++i) pT[l + i * 8][row] = 0.f;
    } else {
      float vals[16];
      float mx = -INFINITY;
#pragma unroll
      for (int i = 0; i < 16; ++i) {
        vals[i] = pT[l + i * 8][row];
        mx = fmaxf(mx, vals[i]);
      }
      mx = fmaxf(mx, __shfl_xor(mx, 1));
      mx = fmaxf(mx, __shfl_xor(mx, 2));
      mx = fmaxf(mx, __shfl_xor(mx, 4));
      float sm = 0.f;
#pragma unroll
      for (int i = 0; i < 16; ++i) {
        vals[i] = __expf(vals[i] - mx);
        sm += vals[i];
      }
      sm += __shfl_xor(sm, 1);
      sm += __shfl_xor(sm, 2);
      sm += __shfl_xor(sm, 4);
      float inv = 1.f / sm;
#pragma unroll
      for (int i = 0; i < 16; ++i) pT[l + i * 8][row] = vals[i] * inv;
    }
  }
  __syncthreads();

  // ---- importance (wave = query, lane = selection block) + top-k ----
  {
    int qq = t >> 6;               // wave id = local query
    int m = t & 63;                // selection block
    int s = s0 + qq;
    int mcur = s >> 5;
    float im;
    if (m > mcur) {
      im = -INFINITY;
    } else {
      im = 0.f;
#pragma unroll
      for (int r = 0; r < 8; ++r) {
        int row = qq * 8 + r;
        float sp = (2 * m - 1 >= 0) ? pT[2 * m - 1][row] : 0.f;
        sp += pT[2 * m][row];
        if (2 * m + 1 < kJ) sp += pT[2 * m + 1][row];
        im += sp;
      }
      if (m == 0) im += 1e9f;
      if (m == mcur) im += 1e9f;
    }
    // top-k: 16 x (64-lane argmax, ties -> lowest index) == jax.lax.top_k
    bool taken = false;
    unsigned long long mask = 0ull;
    for (int it = 0; it < kNSel; ++it) {
      float cv = taken ? -INFINITY : im;
      int ci = taken ? 64 : m;
#pragma unroll
      for (int off = 1; off < 64; off <<= 1) {
        float ov = __shfl_xor(cv, off);
        int oi = __shfl_xor(ci, off);
        if (ov > cv || (ov == cv && oi < ci)) { cv = ov; ci = oi; }
      }
      mask |= 1ull << ci;
      if (m == ci) taken = true;
    }
    if (m == 0) selmask[(size_t)s * 2 + g] = mask;
  }

  // ---- PV: O[row][d] over 4 j-tiles of 32 ----
  float O[4][4];
#pragma unroll
  for (int rr = 0; rr < 4; ++rr)
#pragma unroll
    for (int cc = 0; cc < 4; ++cc) O[rr][cc] = 0.f;

  for (int jt = 0; jt < 4; ++jt) {
    __syncthreads();   // prior kvt readers done (and topk register work finished)
    {
#pragma unroll
      for (int i = 0; i < 4; ++i) {
        int e = (t + i * 256) * 4;
        int jj = e >> 7;
        int d = e & 127;
        int j = jt * 32 + jj;
        int jc = j < kJ ? j : kJ - 1;
        *reinterpret_cast<float4*>(&kvt[jj][d]) =
            *reinterpret_cast<const float4*>(&vc[((size_t)jc * kG + g) * kDH + d]);
      }
    }
    __syncthreads();
#pragma unroll
    for (int kk = 0; kk < 32; ++kk) {
      float4 a = *reinterpret_cast<const float4*>(&pT[jt * 32 + kk][ty * 4]);
      float4 bb = *reinterpret_cast<const float4*>(&kvt[kk][tx * 4]);
      float av[4] = {a.x, a.y, a.z, a.w};
      float bv[4] = {bb.x, bb.y, bb.z, bb.w};
#pragma unroll
      for (int rr = 0; rr < 4; ++rr)
#pragma unroll
        for (int cc = 0; cc < 4; ++cc)
          O[rr][cc] = fmaf(av[rr], bv[cc], O[rr][cc]);
    }
  }
  // ---- write o_cmp ----
#pragma unroll
  for (int rr = 0; rr < 4; ++rr) {
    int row = ty * 4 + rr;
    size_t off = ((size_t)(s0 + (row >> 3)) * kH + g * kRep + (row & 7)) * kDH + tx * 4;
    *reinterpret_cast<float4*>(&oc[off]) = make_float4(O[rr][0], O[rr][1], O[rr][2], O[rr][3]);
  }
  // ---- gates ----
  if (t < 32 * 3) {
    int row = t / 3, e = t - (t / 3) * 3;
    float acc = 0.f;
    for (int d = 0; d < kDH; ++d) acc = fmaf(qst[d][row], wg[d * 3 + e], acc);
    int s = s0 + (row >> 3), r = row & 7;
    gates[((size_t)(s * 2 + g) * kRep + r) * 3 + e] = 1.f / (1.f + __expf(-acc));
  }
}

// ---------------------------------------------------------------------------
// Fused MFMA flash attention (unchanged from round 4 — verified)
// ---------------------------------------------------------------------------
__device__ __forceinline__ void stage_kv(
    const unsigned short* __restrict__ kb, const unsigned short* __restrict__ vT,
    int g, int tb, unsigned short* Ksb, unsigned short* VTb, int t) {
#pragma unroll
  for (int i = 0; i < 2; ++i) {
    int e = i * 2048 + t * 8;
    int row = e >> 7;
    int c = e & 127;
    GLDS16(kb + (size_t)(tb + row) * 256 + g * 128 + c, Ksb + e);
  }
#pragma unroll
  for (int i = 0; i < 2; ++i) {
    int e = i * 2048 + t * 8;
    int d = e >> 5;
    int tok0 = e & 31;
    GLDS16(vT + (size_t)(g * 128 + d) * 2048 + tb + tok0, VTb + e);
  }
}

template <int MODE>  // 0 = selected, 1 = sliding window
__device__ __forceinline__ void attn_tile(
    const unsigned short* Qs, const unsigned short* Ksb,
    const unsigned short* VTb, __bf16* Psw,
    int tb, unsigned selw, int wv, int lo, int hi, int s0,
    f32x4 (&O)[8][2], float (&mst)[2], float (&lst)[2]) {
  f32x4 S[2][2];
#pragma unroll
  for (int tf = 0; tf < 2; ++tf)
#pragma unroll
    for (int rf = 0; rf < 2; ++rf) S[tf][rf] = f32x4{0.f, 0.f, 0.f, 0.f};
#pragma unroll
  for (int ds = 0; ds < 4; ++ds) {
    bf16x8 a[2], b[2];
#pragma unroll
    for (int tf = 0; tf < 2; ++tf)
      a[tf] = *reinterpret_cast<const bf16x8*>(
          &Ksb[(tf * 16 + lo) * 128 + ds * 32 + hi * 8]);
#pragma unroll
    for (int rf = 0; rf < 2; ++rf)
      b[rf] = *reinterpret_cast<const bf16x8*>(
          &Qs[(wv * 32 + rf * 16 + lo) * 128 + ds * 32 + hi * 8]);
#pragma unroll
    for (int tf = 0; tf < 2; ++tf)
#pragma unroll
      for (int rf = 0; rf < 2; ++rf)
        S[tf][rf] = __builtin_amdgcn_mfma_f32_16x16x32_bf16(a[tf], b[rf], S[tf][rf], 0, 0, 0);
  }
#pragma unroll
  for (int rf = 0; rf < 2; ++rf) {
    int qloc = wv * 4 + rf * 2 + (lo >> 3);
    int s_row = s0 + qloc;
    bool selq = (MODE == 1) ? true : (((selw >> qloc) & 1u) != 0);
#pragma unroll
    for (int tf = 0; tf < 2; ++tf)
#pragma unroll
      for (int j = 0; j < 4; ++j) {
        int tok = tb + tf * 16 + hi * 4 + j;
        bool ok = selq && (tok <= s_row) && (MODE == 0 || tok > s_row - kW);
        S[tf][rf][j] = ok ? S[tf][rf][j] * kScale : -1e30f;
      }
    float pm = S[0][rf][0];
#pragma unroll
    for (int tf = 0; tf < 2; ++tf)
#pragma unroll
      for (int j = 0; j < 4; ++j) pm = fmaxf(pm, S[tf][rf][j]);
    pm = fmaxf(pm, __shfl_xor(pm, 16));
    pm = fmaxf(pm, __shfl_xor(pm, 32));
    float mo = mst[rf];
    if (__any(pm > mo)) {
      float mn = fmaxf(mo, pm);
      float f = __expf(mo - mn);
#pragma unroll
      for (int df = 0; df < 8; ++df)
#pragma unroll
        for (int j = 0; j < 4; ++j) O[df][rf][j] *= f;
      lst[rf] *= f;
      mst[rf] = mn;
    }
    float lacc = 0.f;
#pragma unroll
    for (int tf = 0; tf < 2; ++tf) {
      bf16x4 pk;
#pragma unroll
      for (int j = 0; j < 4; ++j) {
        float e = __expf(S[tf][rf][j] - mst[rf]);
        lacc += e;
        pk[j] = (__bf16)e;
      }
      *reinterpret_cast<bf16x4*>(&Psw[(rf * 16 + lo) * 32 + tf * 16 + hi * 4]) = pk;
    }
    lst[rf] += lacc;
  }
  bf16x8 pfrag[2];
#pragma unroll
  for (int rf = 0; rf < 2; ++rf)
    pfrag[rf] = *reinterpret_cast<const bf16x8*>(&Psw[(rf * 16 + lo) * 32 + hi * 8]);
#pragma unroll
  for (int df = 0; df < 8; ++df) {
    bf16x8 vfrag = *reinterpret_cast<const bf16x8*>(&VTb[(df * 16 + lo) * 32 + hi * 8]);
#pragma unroll
    for (int rf = 0; rf < 2; ++rf)
      O[df][rf] = __builtin_amdgcn_mfma_f32_16x16x32_bf16(vfrag, pfrag[rf], O[df][rf], 0, 0, 0);
  }
}

__global__ __launch_bounds__(256) void fused_attn_kernel(
    const unsigned short* __restrict__ qb, const unsigned short* __restrict__ kb,
    const unsigned short* __restrict__ vT, const float* __restrict__ ocp,
    const float* __restrict__ gts,
    const unsigned long long* __restrict__ selmask,
    unsigned short* __restrict__ preb) {
  __shared__ __align__(16) unsigned short Qs[16384];
  __shared__ __align__(16) unsigned short Ks[2][4096];
  __shared__ __align__(16) unsigned short VTs[2][4096];
  __shared__ __align__(16) __bf16 Ps[4][1024];
  __shared__ unsigned long long qm[16];
  __shared__ unsigned int selbits[kNB];
  __shared__ unsigned char blist[kNB];
  __shared__ int nsel_sh;

  const int g = blockIdx.x & 1;
  const int qt = blockIdx.x >> 1;
  const int s0 = qt * 16;
  const int t = threadIdx.x;
  const int lane = t & 63;
  const int wv = t >> 6;
  const int lo = lane & 15, hi = lane >> 4;

#pragma unroll
  for (int i = 0; i < 8; ++i) {
    int e = i * 2048 + t * 8;
    int row = e >> 7;
    int c = e & 127;
    GLDS16(qb + ((size_t)(s0 + (row >> 3)) * 16 + g * 8 + (row & 7)) * 128 + c,
           Qs + e);
  }
  if (t < 16) {
    int mcur = s0 >> 5;
    unsigned long long mm = selmask[(size_t)(s0 + t) * 2 + g];
    mm &= ((2ull << mcur) - 1ull);
    qm[t] = mm;
  }
  __syncthreads();
  if (t < kNB) {
    unsigned b = 0;
    for (int ql = 0; ql < 16; ++ql)
      b |= (unsigned)((qm[ql] >> t) & 1ull) << ql;
    selbits[t] = b;
  }
  if (t == 0) {
    unsigned long long u = 0;
    for (int ql = 0; ql < 16; ++ql) u |= qm[ql];
    int n = 0;
    for (int m = 0; m < kNB; ++m)
      if ((u >> m) & 1ull) blist[n++] = (unsigned char)m;
    nsel_sh = n;
  }
  __syncthreads();

  __bf16* Psw = &Ps[wv][0];

  f32x4 O1[8][2], O2[8][2];
  float mst[2], lst[2];
#pragma unroll
  for (int df = 0; df < 8; ++df)
#pragma unroll
    for (int rf = 0; rf < 2; ++rf) O1[df][rf] = f32x4{0.f, 0.f, 0.f, 0.f};
  mst[0] = mst[1] = -INFINITY;
  lst[0] = lst[1] = 0.f;

  const int nsel = nsel_sh;
  stage_kv(kb, vT, g, (int)blist[0] * 32, Ks[0], VTs[0], t);
  for (int i = 0; i < nsel; ++i) {
    __syncthreads();
    if (i + 1 < nsel)
      stage_kv(kb, vT, g, (int)blist[i + 1] * 32, Ks[(i + 1) & 1], VTs[(i + 1) & 1], t);
    int b = blist[i];
    attn_tile<0>(Qs, Ks[i & 1], VTs[i & 1], Psw, b * 32, selbits[b], wv, lo, hi, s0,
                 O1, mst, lst);
  }
  float g0v[2], g2v[2];
#pragma unroll
  for (int rf = 0; rf < 2; ++rf) {
    int row = wv * 32 + rf * 16 + lo;
    int s_row = s0 + (row >> 3);
    int r = row & 7;
    const float* gp = gts + ((size_t)(s_row * 2 + g) * 8 + r) * 3;
    g0v[rf] = gp[0];
    g2v[rf] = gp[2];
    float lt = lst[rf];
    lt += __shfl_xor(lt, 16);
    lt += __shfl_xor(lt, 32);
    float f = gp[1] / lt;
#pragma unroll
    for (int df = 0; df < 8; ++df)
#pragma unroll
      for (int j = 0; j < 4; ++j) O1[df][rf][j] *= f;
    mst[rf] = -INFINITY;
    lst[rf] = 0.f;
  }
#pragma unroll
  for (int df = 0; df < 8; ++df)
#pragma unroll
    for (int rf = 0; rf < 2; ++rf) O2[df][rf] = f32x4{0.f, 0.f, 0.f, 0.f};

  const int hi_t = s0 >> 5;
  const int lo_t = (s0 > 255) ? ((s0 - 255) >> 5) : 0;
  const int nsw = hi_t - lo_t + 1;
  __syncthreads();
  stage_kv(kb, vT, g, hi_t * 32, Ks[0], VTs[0], t);
  for (int ii = 0; ii < nsw; ++ii) {
    __syncthreads();
    if (ii + 1 < nsw)
      stage_kv(kb, vT, g, (hi_t - ii - 1) * 32, Ks[(ii + 1) & 1], VTs[(ii + 1) & 1], t);
    attn_tile<1>(Qs, Ks[ii & 1], VTs[ii & 1], Psw, (hi_t - ii) * 32, 0u, wv, lo, hi, s0,
                 O2, mst, lst);
  }
#pragma unroll
  for (int rf = 0; rf < 2; ++rf) {
    int row = wv * 32 + rf * 16 + lo;
    int s_row = s0 + (row >> 3);
    int r = row & 7;
    float lt = lst[rf];
    lt += __shfl_xor(lt, 16);
    lt += __shfl_xor(lt, 32);
    float f2 = g2v[rf] / lt;
    size_t base = ((size_t)s_row * 16 + g * 8 + r) * 128;
#pragma unroll
    for (int df = 0; df < 8; ++df) {
      int d0 = df * 16 + hi * 4;
      float4 ocv = *reinterpret_cast<const float4*>(&ocp[base + d0]);
      ushort4 w;
      w.x = f2bf(g0v[rf] * ocv.x + O1[df][rf][0] + f2 * O2[df][rf][0]);
      w.y = f2bf(g0v[rf] * ocv.y + O1[df][rf][1] + f2 * O2[df][rf][1]);
      w.z = f2bf(g0v[rf] * ocv.z + O1[df][rf][2] + f2 * O2[df][rf][2]);
      w.w = f2bf(g0v[rf] * ocv.w + O1[df][rf][3] + f2 * O2[df][rf][3]);
      *reinterpret_cast<ushort4*>(&preb[base + d0]) = w;
    }
  }
}

// ---------------------------------------------------------------------------
extern "C" void kernel_launch(void* const* d_in, const int* in_sizes, int n_in,
                              void* d_out, int out_size, void* d_ws, size_t ws_size,
                              hipStream_t stream) {
  (void)in_sizes; (void)n_in; (void)out_size; (void)ws_size;
  const float* x  = (const float*)d_in[0];
  const float* fc = (const float*)d_in[1];
  const float* fs = (const float*)d_in[2];
  const float* wq = (const float*)d_in[3];
  const float* wk = (const float*)d_in[4];
  const float* wv = (const float*)d_in[5];
  const float* wo = (const float*)d_in[6];
  const float* wg = (const float*)d_in[7];
  float* out = (float*)d_out;

  float* q    = (float*)d_ws;                    // 4194304 f32
  float* kbuf = q + kS * kH * kDH;               // 524288
  float* vbuf = kbuf + kS * kG * kDH;            // 524288
  float* kc   = vbuf + kS * kG * kDH;            // 32512
  float* vc   = kc + kJ * kG * kDH;              // 32512
  float* oc   = vc + kJ * kG * kDH;              // 4194304
  float* gts  = oc + kS * kH * kDH;              // 98304
  unsigned long long* selmask = (unsigned long long*)(gts + kS * kG * kRep * 3); // 4096
  unsigned short* xb   = (unsigned short*)(selmask + kS * kG);
  unsigned short* wqT  = xb + kS * kDim;           // [2048][2048]
  unsigned short* wkT  = wqT + (kH * kDH) * kDim;  // [256][2048]
  unsigned short* wvT  = wkT + (kG * kDH) * kDim;  // [256][2048]
  unsigned short* woT  = wvT + (kG * kDH) * kDim;  // [2048][2048]
  unsigned short* preb = woT + kDim * (kH * kDH);  // [2048][2048]
  unsigned short* kb   = preb + kS * kDim;         // [2048 tok][2 g][128 d]
  unsigned short* vT   = kb + kS * kG * kDH;       // [2 g * 128 d][2048 tok]
  unsigned short* qbuf = xb;   // alias: xb dead after projection GEMMs

  dim3 blk256(256);
  cast_bf16_kernel<<<kS * kDim / 4 / 256, blk256, 0, stream>>>(x, xb, kS * kDim / 4);
  transpose_cast_kernel<<<dim3((kH * kDH) / 32, kDim / 32), blk256, 0, stream>>>(wq, wqT, kDim, kH * kDH);
  transpose_cast_kernel<<<dim3((kG * kDH) / 32, kDim / 32), blk256, 0, stream>>>(wk, wkT, kDim, kG * kDH);
  transpose_cast_kernel<<<dim3((kG * kDH) / 32, kDim / 32), blk256, 0, stream>>>(wv, wvT, kDim, kG * kDH);
  transpose_cast_kernel<<<dim3(kDim / 32, (kH * kDH) / 32), blk256, 0, stream>>>(wo, woT, kH * kDH, kDim);
  gemm_bf16_kernel<<<dim3(16, 16), blk256, 0, stream>>>(xb, wqT, q, kS, kH * kDH, kDim);
  gemm_bf16_kernel<<<dim3(2, 16), blk256, 0, stream>>>(xb, wkT, kbuf, kS, kG * kDH, kDim);
  gemm_bf16_kernel<<<dim3(2, 16), blk256, 0, stream>>>(xb, wvT, vbuf, kS, kG * kDH, kDim);
  rope_kernel<<<8192, blk256, 0, stream>>>(q, fc, fs, kH, kS * kH * 64);
  rope_kernel<<<1024, blk256, 0, stream>>>(kbuf, fc, fs, kG, kS * kG * 64);
  cast_bf16_kernel<<<kS * kH * kDH / 4 / 256, blk256, 0, stream>>>(q, qbuf, kS * kH * kDH / 4);
  cast_bf16_kernel<<<kS * kG * kDH / 4 / 256, blk256, 0, stream>>>(kbuf, kb, kS * kG * kDH / 4);
  transpose_cast_kernel<<<dim3(kG * kDH / 32, kS / 32), blk256, 0, stream>>>(vbuf, vT, kS, kG * kDH);
  pool_kernel<<<128, blk256, 0, stream>>>(kbuf, vbuf, kc, vc);
  cmp_attn_kernel<<<kS / kQT * kG, blk256, 0, stream>>>(q, kc, vc, wg, oc, gts, selmask);
  fused_attn_kernel<<<kS / 16 * kG, blk256, 0, stream>>>(qbuf, kb, vT, oc, gts, selmask, preb);
  gemm_bf16_kernel<<<dim3(16, 16), blk256, 0, stream>>>(preb, woT, out, kS, kDim, kH * kDH);
}